// Round 3
// baseline (6534.221 us; speedup 1.0000x reference)
//
#include <hip/hip_runtime.h>
#include <hip/hip_bf16.h>
#include <math.h>

// Problem constants
#define BB 8
#define SS 512
#define EE 768
#define HH 12
#define DD 64
#define FF 3072
#define NTOK (BB * SS)            // 4096 tokens
#define NE ((size_t)NTOK * EE)    // 3,145,728

// GEMM tile
#define GBM 128
#define GBN 64
#define GBK 16

// flags
#define FLAG_ACC  1   // C += A@W   (read existing C)
#define FLAG_BHSD 2   // store permuted to [B,H,S,D]
#define FLAG_RES  4   // + Rsrc[row,col]
#define FLAG_GELU 8   // gelu_new epilogue
#define FLAG_FIN  16  // out = (Rsrc + v) * maskq[row]

__device__ __forceinline__ float gelu_new(float x) {
    return 0.5f * x * (1.0f + tanhf(0.7978845608028654f * (x + 0.044715f * x * x * x)));
}

// ---------------- LayerNorm: one block per row (768 elems, 256 threads) -------------
__global__ __launch_bounds__(256) void ln_kernel(
    const float* __restrict__ in, float* __restrict__ out,
    const float* __restrict__ g, const float* __restrict__ bta,
    size_t base_off, size_t batch_stride)
{
    int row = blockIdx.x;               // 0..NTOK-1
    int b = row >> 9, s = row & 511;
    const float* x = in + base_off + (size_t)b * batch_stride + (size_t)s * EE;
    int tid = threadIdx.x;

    float v0 = x[tid], v1 = x[tid + 256], v2 = x[tid + 512];
    float s1 = v0 + v1 + v2;
    float s2 = v0 * v0 + v1 * v1 + v2 * v2;
    #pragma unroll
    for (int o = 32; o > 0; o >>= 1) {
        s1 += __shfl_down(s1, o);
        s2 += __shfl_down(s2, o);
    }
    __shared__ float r1[4], r2[4];
    if ((tid & 63) == 0) { r1[tid >> 6] = s1; r2[tid >> 6] = s2; }
    __syncthreads();
    float mean = (r1[0] + r1[1] + r1[2] + r1[3]) * (1.0f / 768.0f);
    float ssq  = (r2[0] + r2[1] + r2[2] + r2[3]) * (1.0f / 768.0f);
    float var = ssq - mean * mean;
    float rstd = rsqrtf(var + 1e-5f);

    float* y = out + (size_t)row * EE;
    y[tid]       = (v0 - mean) * rstd * g[tid]       + bta[tid];
    y[tid + 256] = (v1 - mean) * rstd * g[tid + 256] + bta[tid + 256];
    y[tid + 512] = (v2 - mean) * rstd * g[tid + 512] + bta[tid + 512];
}

// ---------------- fp32 tiled GEMM: C[M,Nn] = A[M,K] @ W[K,Nn] (+bias, epilogues) ----
__global__ __launch_bounds__(256) void gemm_kernel(
    const float* __restrict__ A, const float* __restrict__ W,
    const float* __restrict__ bias, float* __restrict__ C,
    const float* __restrict__ Rsrc, const float* __restrict__ maskq,
    int M, int Nn, int K, int flags)
{
    __shared__ float As[GBK][GBM];
    __shared__ float Bs[GBK][GBN];
    int tid = threadIdx.x;
    int row0 = blockIdx.x * GBM;
    int col0 = blockIdx.y * GBN;
    int tx = tid & 15, ty = tid >> 4;   // 16x16 threads; each does 8x4 outputs

    float acc[8][4] = {};

    for (int kb = 0; kb < K; kb += GBK) {
        // A tile: 128x16 = 512 float4, 2 per thread; store transposed As[k][m]
        #pragma unroll
        for (int i = 0; i < 2; ++i) {
            int idx = tid + i * 256;
            int r = idx >> 2;
            int k4 = (idx & 3) * 4;
            float4 v = *(const float4*)&A[(size_t)(row0 + r) * K + kb + k4];
            As[k4 + 0][r] = v.x; As[k4 + 1][r] = v.y;
            As[k4 + 2][r] = v.z; As[k4 + 3][r] = v.w;
        }
        // W tile: 16x64 = 256 float4, 1 per thread
        {
            int kr = tid >> 4;
            int c4 = (tid & 15) * 4;
            float4 v = *(const float4*)&W[(size_t)(kb + kr) * Nn + col0 + c4];
            *(float4*)&Bs[kr][c4] = v;
        }
        __syncthreads();
        #pragma unroll
        for (int kk = 0; kk < GBK; ++kk) {
            float4 a0 = *(float4*)&As[kk][ty * 8];
            float4 a1 = *(float4*)&As[kk][ty * 8 + 4];
            float4 bv = *(float4*)&Bs[kk][tx * 4];
            float av[8] = {a0.x, a0.y, a0.z, a0.w, a1.x, a1.y, a1.z, a1.w};
            float bw[4] = {bv.x, bv.y, bv.z, bv.w};
            #pragma unroll
            for (int i = 0; i < 8; ++i)
                #pragma unroll
                for (int j = 0; j < 4; ++j)
                    acc[i][j] += av[i] * bw[j];
        }
        __syncthreads();
    }

    bool f_acc  = flags & FLAG_ACC;
    bool f_bhsd = flags & FLAG_BHSD;
    bool f_res  = flags & FLAG_RES;
    bool f_gelu = flags & FLAG_GELU;
    bool f_fin  = flags & FLAG_FIN;

    #pragma unroll
    for (int i = 0; i < 8; ++i) {
        int rg = row0 + ty * 8 + i;
        #pragma unroll
        for (int j = 0; j < 4; ++j) {
            int cg = col0 + tx * 4 + j;
            size_t lin = (size_t)rg * Nn + cg;
            float v = acc[i][j];
            if (f_acc)  v += C[lin];
            if (bias)   v += bias[cg];
            if (f_res)  v += Rsrc[lin];
            if (f_gelu) v = gelu_new(v);
            if (f_fin)  v = (Rsrc[lin] + v) * maskq[rg];
            if (f_bhsd) {
                int b = rg >> 9, s = rg & 511;
                int h = cg >> 6, d = cg & 63;
                C[(((size_t)b * HH + h) * SS + s) * DD + d] = v;
            } else {
                C[lin] = v;
            }
        }
    }
}

// ---------------- attention: one block per (b,h,q); K/V in [B,H,S,D] ---------------
__global__ __launch_bounds__(256) void attn_kernel(
    const float* __restrict__ Q, const float* __restrict__ Kt,
    const float* __restrict__ Vt, const int* __restrict__ maskE,
    float* __restrict__ Out, int causal, float maskval)
{
    int bhq = blockIdx.x;
    int q  = bhq & (SS - 1);
    int bh = bhq >> 9;
    int b = bh / HH, h = bh % HH;
    const float* qv = Q  + ((size_t)bh * SS + q) * DD;
    const float* Kp = Kt + (size_t)bh * SS * DD;
    const float* Vp = Vt + (size_t)bh * SS * DD;

    __shared__ float qs[DD];
    __shared__ float sc[SS];
    __shared__ float red[4];
    __shared__ float po[4][DD];
    int tid = threadIdx.x;

    if (tid < DD) qs[tid] = qv[tid];
    __syncthreads();

    float lmax = -3.0e38f;
    for (int k = tid; k < SS; k += 256) {
        float val;
        if (causal && (k > q)) {
            val = -3.0e38f;   // exp -> exactly 0, same as ref's -1e9
        } else {
            float dot = 0.f;
            const float4* kr = (const float4*)(Kp + (size_t)k * DD);
            #pragma unroll
            for (int d4 = 0; d4 < DD / 4; ++d4) {
                float4 kv = kr[d4];
                float4 q4 = *(const float4*)&qs[d4 * 4];
                dot += kv.x * q4.x + kv.y * q4.y + kv.z * q4.z + kv.w * q4.w;
            }
            val = dot * 0.125f;
            if (!causal && (maskE[(size_t)b * SS + k] != 0)) val = maskval; // -1e4
        }
        sc[k] = val;
        lmax = fmaxf(lmax, val);
    }
    #pragma unroll
    for (int o = 32; o > 0; o >>= 1) lmax = fmaxf(lmax, __shfl_down(lmax, o));
    if ((tid & 63) == 0) red[tid >> 6] = lmax;
    __syncthreads();
    float gmax = fmaxf(fmaxf(red[0], red[1]), fmaxf(red[2], red[3]));
    __syncthreads();   // red about to be reused

    float lsum = 0.f;
    for (int k = tid; k < SS; k += 256) {
        float p = expf(sc[k] - gmax);
        sc[k] = p;
        lsum += p;
    }
    #pragma unroll
    for (int o = 32; o > 0; o >>= 1) lsum += __shfl_down(lsum, o);
    if ((tid & 63) == 0) red[tid >> 6] = lsum;
    __syncthreads();
    float inv = 1.0f / (red[0] + red[1] + red[2] + red[3]);

    // PV: 4 k-chunks x 64 d
    int d = tid & 63;
    int c = tid >> 6;
    float o = 0.f;
    for (int k = c * (SS / 4); k < (c + 1) * (SS / 4); ++k)
        o += sc[k] * Vp[(size_t)k * DD + d];
    po[c][d] = o;
    __syncthreads();
    if (tid < DD) {
        float r = (po[0][tid] + po[1][tid] + po[2][tid] + po[3][tid]) * inv;
        Out[((size_t)b * SS + q) * EE + h * DD + tid] = r;
    }
}

// ---------------- gate: acc (+)= alpha*lm*a + (1-alpha)*vm*e ------------------------
__global__ void gate_kernel(const float* __restrict__ logits, const float* __restrict__ a,
                            const float* __restrict__ e, float* __restrict__ acc,
                            const int* __restrict__ tau, int init)
{
    float thr = (float)tau[0];
    for (size_t i = (size_t)blockIdx.x * blockDim.x + threadIdx.x; i < NE;
         i += (size_t)gridDim.x * blockDim.x) {
        float al = 1.0f / (1.0f + expf(-logits[i]));
        float lm = (al > thr) ? 1.0f : 0.0f;
        float vm = (al < 1.0f - thr) ? 1.0f : 0.0f;
        float v = al * lm * a[i] + (1.0f - al) * vm * e[i];
        acc[i] = init ? v : (acc[i] + v);
    }
}

// ---------------- aq = acc / sqrt(3) * maskq[row] -----------------------------------
__global__ void scale_mask_kernel(float* __restrict__ acc, const float* __restrict__ maskq)
{
    for (size_t i = (size_t)blockIdx.x * blockDim.x + threadIdx.x; i < NE;
         i += (size_t)gridDim.x * blockDim.x) {
        acc[i] = acc[i] * 0.57735026918962576f * maskq[i / EE];
    }
}

extern "C" void kernel_launch(void* const* d_in, const int* in_sizes, int n_in,
                              void* d_out, int out_size, void* d_ws, size_t ws_size,
                              hipStream_t stream)
{
    const float* x        = (const float*)d_in[0];
    const float* enc      = (const float*)d_in[1];
    const float* maskq    = (const float*)d_in[2];
    const int*   mask_enc = (const int*)d_in[4];
    const int*   tau      = (const int*)d_in[6];
    const float* Wq = (const float*)d_in[7];
    const float* Wk = (const float*)d_in[8];
    const float* Wv = (const float*)d_in[9];
    const float* Wo = (const float*)d_in[10];
    const float* bo = (const float*)d_in[11];
    const float* fcq_w = (const float*)d_in[12];
    const float* fcq_b = (const float*)d_in[13];
    const float* fck_w = (const float*)d_in[14];
    const float* fck_b = (const float*)d_in[15];
    const float* fcv_w = (const float*)d_in[16];
    const float* fcv_b = (const float*)d_in[17];
    const float* cproj_w = (const float*)d_in[18];
    const float* cproj_b = (const float*)d_in[19];
    const float* ln1_g = (const float*)d_in[20];
    const float* ln1_b = (const float*)d_in[21];
    const float* ln2_g = (const float*)d_in[22];
    const float* ln2_b = (const float*)d_in[23];
    const float* cfc_w = (const float*)d_in[24];
    const float* cfc_b = (const float*)d_in[25];
    const float* cproj2_w = (const float*)d_in[26];
    const float* cproj2_b = (const float*)d_in[27];
    const float* aw[3] = {(const float*)d_in[28], (const float*)d_in[30], (const float*)d_in[32]};
    const float* ab[3] = {(const float*)d_in[29], (const float*)d_in[31], (const float*)d_in[33]};

    float* out   = (float*)d_out;       // [NTOK, E]
    float* kpres = out + NE;            // present[0]: [B,H,S,D]
    float* vpres = out + 2 * NE;        // present[1]

    float* ws     = (float*)d_ws;
    float* xl     = ws;                 // also: el, e-proj temp, aqln
    float* qb     = ws + 1 * NE;        // self q, then cross q  [B,H,S,D]
    float* attout = ws + 2 * NE;        // attention output [N,E]
    float* a      = ws + 3 * NE;
    float* al     = ws + 4 * NE;
    float* kc     = ws + 5 * NE;        // cross K [B,H,S,D]
    float* vc     = ws + 6 * NE;        // cross V
    float* acc    = ws + 7 * NE;        // gated sum -> aq
    float* ebuf   = ws + 8 * NE;        // e_idx
    float* mlph   = ws + 9 * NE;        // [N, F]
    float* alpha  = out;                // transient gate-logit scratch (overwritten by final GEMM)

    dim3 blk(256);
    dim3 gE(NTOK / GBM, EE / GBN);      // 32 x 12
    dim3 gF(NTOK / GBM, FF / GBN);      // 32 x 48
    dim3 gAttn(BB * HH * SS);           // 49152

    // 1. xl = ln1(x)
    ln_kernel<<<NTOK, blk, 0, stream>>>(x, xl, ln1_g, ln1_b, 0, (size_t)SS * EE);
    // 2. self q,k,v (k,v straight into present region of d_out)
    gemm_kernel<<<gE, blk, 0, stream>>>(xl, Wq, nullptr, qb,    nullptr, nullptr, NTOK, EE, EE, FLAG_BHSD);
    gemm_kernel<<<gE, blk, 0, stream>>>(xl, Wk, nullptr, kpres, nullptr, nullptr, NTOK, EE, EE, FLAG_BHSD);
    gemm_kernel<<<gE, blk, 0, stream>>>(xl, Wv, nullptr, vpres, nullptr, nullptr, NTOK, EE, EE, FLAG_BHSD);
    // 3. causal self-attention
    attn_kernel<<<gAttn, blk, 0, stream>>>(qb, kpres, vpres, nullptr, attout, 1, 0.f);
    // 4. a = attout@Wo + bo + x
    gemm_kernel<<<gE, blk, 0, stream>>>(attout, Wo, bo, a, x, nullptr, NTOK, EE, EE, FLAG_RES);
    // 5. al = ln1(a)
    ln_kernel<<<NTOK, blk, 0, stream>>>(a, al, ln1_g, ln1_b, 0, (size_t)SS * EE);
    // 6. cross q (shared across the 3 encoders)
    gemm_kernel<<<gE, blk, 0, stream>>>(al, fcq_w, fcq_b, qb, nullptr, nullptr, NTOK, EE, EE, FLAG_BHSD);
    // 7. three cross-attention branches + gates
    for (int idx = 0; idx < 3; ++idx) {
        ln_kernel<<<NTOK, blk, 0, stream>>>(enc, xl, ln1_g, ln1_b,
                                            (size_t)idx * SS * EE, (size_t)3 * SS * EE);
        gemm_kernel<<<gE, blk, 0, stream>>>(xl, fck_w, fck_b, kc, nullptr, nullptr, NTOK, EE, EE, FLAG_BHSD);
        gemm_kernel<<<gE, blk, 0, stream>>>(xl, fcv_w, fcv_b, vc, nullptr, nullptr, NTOK, EE, EE, FLAG_BHSD);
        attn_kernel<<<gAttn, blk, 0, stream>>>(qb, kc, vc, mask_enc, attout, 0, -1e4f);
        gemm_kernel<<<gE, blk, 0, stream>>>(attout, cproj_w, cproj_b, ebuf, nullptr, nullptr, NTOK, EE, EE, 0);
        // gate logits: a @ aw[0:768] + e @ aw[768:1536] + ab
        gemm_kernel<<<gE, blk, 0, stream>>>(a,    aw[idx],             ab[idx], alpha, nullptr, nullptr, NTOK, EE, EE, 0);
        gemm_kernel<<<gE, blk, 0, stream>>>(ebuf, aw[idx] + 768 * 768, nullptr, alpha, nullptr, nullptr, NTOK, EE, EE, FLAG_ACC);
        gate_kernel<<<2048, blk, 0, stream>>>(alpha, a, ebuf, acc, tau, idx == 0 ? 1 : 0);
    }
    // 8. aq = acc / sqrt3 * maskq   (in place)
    scale_mask_kernel<<<2048, blk, 0, stream>>>(acc, maskq);
    // 9. aqln = ln2(aq)
    ln_kernel<<<NTOK, blk, 0, stream>>>(acc, xl, ln2_g, ln2_b, 0, (size_t)SS * EE);
    // 10. mlph = gelu(aqln @ cfc + cfc_b)
    gemm_kernel<<<gF, blk, 0, stream>>>(xl, cfc_w, cfc_b, mlph, nullptr, nullptr, NTOK, FF, EE, FLAG_GELU);
    // 11. out = (aq + mlph @ cproj2 + cproj2_b) * maskq
    gemm_kernel<<<gE, blk, 0, stream>>>(mlph, cproj2_w, cproj2_b, out, acc, maskq, NTOK, EE, FF, FLAG_FIN);
}

// Round 4
// 3312.927 us; speedup vs baseline: 1.9723x; 1.9723x over previous
//
#include <hip/hip_runtime.h>
#include <hip/hip_bf16.h>
#include <math.h>

// Problem constants
#define BB 8
#define SS 512
#define EE 768
#define HH 12
#define DD 64
#define FF 3072
#define NTOK (BB * SS)            // 4096 tokens
#define NE ((size_t)NTOK * EE)    // 3,145,728

// GEMM tile
#define GBM 128
#define GBN 64
#define GBK 16

// attention tiles
#define QT 64
#define KT 64

// flags
#define FLAG_ACC  1   // C += A@W   (read existing C)
#define FLAG_BHSD 2   // store permuted to [B,H,S,D]
#define FLAG_RES  4   // + Rsrc[row,col]
#define FLAG_GELU 8   // gelu_new epilogue
#define FLAG_FIN  16  // out = (Rsrc + v) * maskq[row]

__device__ __forceinline__ float gelu_new(float x) {
    return 0.5f * x * (1.0f + tanhf(0.7978845608028654f * (x + 0.044715f * x * x * x)));
}

// ---------------- LayerNorm: one block per row (768 elems, 256 threads) -------------
__global__ __launch_bounds__(256) void ln_kernel(
    const float* __restrict__ in, float* __restrict__ out,
    const float* __restrict__ g, const float* __restrict__ bta,
    size_t base_off, size_t batch_stride)
{
    int row = blockIdx.x;               // 0..NTOK-1
    int b = row >> 9, s = row & 511;
    const float* x = in + base_off + (size_t)b * batch_stride + (size_t)s * EE;
    int tid = threadIdx.x;

    float v0 = x[tid], v1 = x[tid + 256], v2 = x[tid + 512];
    float s1 = v0 + v1 + v2;
    float s2 = v0 * v0 + v1 * v1 + v2 * v2;
    #pragma unroll
    for (int o = 32; o > 0; o >>= 1) {
        s1 += __shfl_down(s1, o);
        s2 += __shfl_down(s2, o);
    }
    __shared__ float r1[4], r2[4];
    if ((tid & 63) == 0) { r1[tid >> 6] = s1; r2[tid >> 6] = s2; }
    __syncthreads();
    float mean = (r1[0] + r1[1] + r1[2] + r1[3]) * (1.0f / 768.0f);
    float ssq  = (r2[0] + r2[1] + r2[2] + r2[3]) * (1.0f / 768.0f);
    float var = ssq - mean * mean;
    float rstd = rsqrtf(var + 1e-5f);

    float* y = out + (size_t)row * EE;
    y[tid]       = (v0 - mean) * rstd * g[tid]       + bta[tid];
    y[tid + 256] = (v1 - mean) * rstd * g[tid + 256] + bta[tid + 256];
    y[tid + 512] = (v2 - mean) * rstd * g[tid + 512] + bta[tid + 512];
}

// ---------------- fp32 tiled GEMM: C[M,Nn] = A[M,K] @ W[K,Nn] (+bias, epilogues) ----
__global__ __launch_bounds__(256) void gemm_kernel(
    const float* __restrict__ A, const float* __restrict__ W,
    const float* __restrict__ bias, float* __restrict__ C,
    const float* __restrict__ Rsrc, const float* __restrict__ maskq,
    int M, int Nn, int K, int flags)
{
    __shared__ float As[GBK][GBM];
    __shared__ float Bs[GBK][GBN];
    int tid = threadIdx.x;
    int row0 = blockIdx.x * GBM;
    int col0 = blockIdx.y * GBN;
    int tx = tid & 15, ty = tid >> 4;   // 16x16 threads; each does 8x4 outputs

    float acc[8][4] = {};

    for (int kb = 0; kb < K; kb += GBK) {
        // A tile: 128x16 = 512 float4, 2 per thread; store transposed As[k][m]
        #pragma unroll
        for (int i = 0; i < 2; ++i) {
            int idx = tid + i * 256;
            int r = idx >> 2;
            int k4 = (idx & 3) * 4;
            float4 v = *(const float4*)&A[(size_t)(row0 + r) * K + kb + k4];
            As[k4 + 0][r] = v.x; As[k4 + 1][r] = v.y;
            As[k4 + 2][r] = v.z; As[k4 + 3][r] = v.w;
        }
        // W tile: 16x64 = 256 float4, 1 per thread
        {
            int kr = tid >> 4;
            int c4 = (tid & 15) * 4;
            float4 v = *(const float4*)&W[(size_t)(kb + kr) * Nn + col0 + c4];
            *(float4*)&Bs[kr][c4] = v;
        }
        __syncthreads();
        #pragma unroll
        for (int kk = 0; kk < GBK; ++kk) {
            float4 a0 = *(float4*)&As[kk][ty * 8];
            float4 a1 = *(float4*)&As[kk][ty * 8 + 4];
            float4 bv = *(float4*)&Bs[kk][tx * 4];
            float av[8] = {a0.x, a0.y, a0.z, a0.w, a1.x, a1.y, a1.z, a1.w};
            float bw[4] = {bv.x, bv.y, bv.z, bv.w};
            #pragma unroll
            for (int i = 0; i < 8; ++i)
                #pragma unroll
                for (int j = 0; j < 4; ++j)
                    acc[i][j] += av[i] * bw[j];
        }
        __syncthreads();
    }

    bool f_acc  = flags & FLAG_ACC;
    bool f_bhsd = flags & FLAG_BHSD;
    bool f_res  = flags & FLAG_RES;
    bool f_gelu = flags & FLAG_GELU;
    bool f_fin  = flags & FLAG_FIN;

    #pragma unroll
    for (int i = 0; i < 8; ++i) {
        int rg = row0 + ty * 8 + i;
        #pragma unroll
        for (int j = 0; j < 4; ++j) {
            int cg = col0 + tx * 4 + j;
            size_t lin = (size_t)rg * Nn + cg;
            float v = acc[i][j];
            if (f_acc)  v += C[lin];
            if (bias)   v += bias[cg];
            if (f_res)  v += Rsrc[lin];
            if (f_gelu) v = gelu_new(v);
            if (f_fin)  v = (Rsrc[lin] + v) * maskq[rg];
            if (f_bhsd) {
                int b = rg >> 9, s = rg & 511;
                int h = cg >> 6, d = cg & 63;
                C[(((size_t)b * HH + h) * SS + s) * DD + d] = v;
            } else {
                C[lin] = v;
            }
        }
    }
}

// ---------------- tiled flash attention -------------------------------------------
// grid: (qtiles=8, bh=96). 256 threads: thread -> (q = tid&63, slot = tid>>6).
// Q row in registers; K/V tiles staged in LDS (wave-uniform broadcast reads);
// online softmax, m/l replicated across the 4 slot-threads of each row;
// each thread accumulates d-quarter [slot*16, slot*16+16) of O.
__global__ __launch_bounds__(256) void fattn_kernel(
    const float* __restrict__ Q, const float* __restrict__ Kt,
    const float* __restrict__ Vt, const int* __restrict__ maskE,
    float* __restrict__ Out, int causal)
{
    int qt = blockIdx.x, bh = blockIdx.y;
    int b = bh / HH, h = bh % HH;
    int tid = threadIdx.x;
    int q = tid & 63;
    int slot = tid >> 6;

    __shared__ float Ks[KT][DD];        // 16 KB
    __shared__ float Vs[KT][DD];        // 16 KB
    __shared__ float Ps[QT][KT + 2];    // 16.5 KB, 2-way-free bank pattern
    __shared__ float rowred[QT][4];
    __shared__ int   kmask[KT];

    // Q row -> registers (64 VGPR, all indices static)
    float qreg[DD];
    {
        const float4* qrow = (const float4*)(Q + ((size_t)bh * SS + qt * QT + q) * DD);
        #pragma unroll
        for (int i = 0; i < DD / 4; ++i) {
            float4 v = qrow[i];
            qreg[i*4+0] = v.x; qreg[i*4+1] = v.y; qreg[i*4+2] = v.z; qreg[i*4+3] = v.w;
        }
    }

    float m = -3.0e38f, l = 0.f;
    float o[16];
    #pragma unroll
    for (int i = 0; i < 16; ++i) o[i] = 0.f;

    int q_glob = qt * QT + q;
    int ntiles = causal ? (qt + 1) : (SS / KT);

    for (int kt = 0; kt < ntiles; ++kt) {
        // ---- stage K/V tile (+ cross-attn mask) ----
        const float* Kg = Kt + ((size_t)bh * SS + kt * KT) * DD;
        const float* Vg = Vt + ((size_t)bh * SS + kt * KT) * DD;
        #pragma unroll
        for (int i = 0; i < 4; ++i) {
            int idx = tid + i * 256;        // 0..1023
            int r = idx >> 4, c = idx & 15;
            *(float4*)&Ks[r][c * 4] = *(const float4*)&Kg[(size_t)r * DD + c * 4];
            *(float4*)&Vs[r][c * 4] = *(const float4*)&Vg[(size_t)r * DD + c * 4];
        }
        if (maskE && tid < KT) kmask[tid] = maskE[(size_t)b * SS + kt * KT + tid];
        __syncthreads();

        // ---- scores: 16 cells, k = slot*16 + j (wave-uniform Ks rows -> broadcast)
        float s[16];
        #pragma unroll
        for (int j = 0; j < 16; ++j) {
            int k = slot * 16 + j;
            float acc = 0.f;
            #pragma unroll
            for (int d4 = 0; d4 < 16; ++d4) {
                float4 kv = *(const float4*)&Ks[k][d4 * 4];
                acc += kv.x * qreg[d4*4]   + kv.y * qreg[d4*4+1]
                     + kv.z * qreg[d4*4+2] + kv.w * qreg[d4*4+3];
            }
            acc *= 0.125f;
            if (causal) {
                if (kt * KT + k > q_glob) acc = -3.0e38f;   // exp -> exactly 0
            } else {
                if (kmask[k] != 0) acc = -1e4f;             // matches ref's where()
            }
            s[j] = acc;
        }
        // ---- online softmax update ----
        float lm = s[0];
        #pragma unroll
        for (int j = 1; j < 16; ++j) lm = fmaxf(lm, s[j]);
        rowred[q][slot] = lm;
        __syncthreads();
        float tmax = fmaxf(fmaxf(rowred[q][0], rowred[q][1]),
                           fmaxf(rowred[q][2], rowred[q][3]));
        float mnew = fmaxf(m, tmax);
        float resc = expf(m - mnew);        // first tile: exp(-inf) = 0
        m = mnew;
        l *= resc;
        #pragma unroll
        for (int i = 0; i < 16; ++i) o[i] *= resc;
        float psum = 0.f;
        #pragma unroll
        for (int j = 0; j < 16; ++j) {
            float p = expf(s[j] - m);
            psum += p;
            Ps[q][slot * 16 + j] = p;
        }
        l += psum;
        __syncthreads();    // Ps visible; rowred consumed

        // ---- PV: o[slot*16 .. +15] (Vs reads wave-uniform -> broadcast) ----
        for (int k = 0; k < KT; ++k) {
            float p = Ps[q][k];
            #pragma unroll
            for (int d4 = 0; d4 < 4; ++d4) {
                float4 v = *(const float4*)&Vs[k][slot * 16 + d4 * 4];
                o[d4*4+0] += p * v.x; o[d4*4+1] += p * v.y;
                o[d4*4+2] += p * v.z; o[d4*4+3] += p * v.w;
            }
        }
        __syncthreads();    // before next tile overwrites Ks/Vs/Ps
    }

    // ---- finalize: sum l across slots, normalize, store ----
    rowred[q][slot] = l;
    __syncthreads();
    float inv = 1.0f / (rowred[q][0] + rowred[q][1] + rowred[q][2] + rowred[q][3]);
    float* op = Out + ((size_t)b * SS + q_glob) * EE + h * DD + slot * 16;
    #pragma unroll
    for (int d4 = 0; d4 < 4; ++d4) {
        float4 v = { o[d4*4] * inv, o[d4*4+1] * inv, o[d4*4+2] * inv, o[d4*4+3] * inv };
        *(float4*)&op[d4 * 4] = v;
    }
}

// ---------------- gate: acc (+)= alpha*lm*a + (1-alpha)*vm*e ------------------------
__global__ void gate_kernel(const float* __restrict__ logits, const float* __restrict__ a,
                            const float* __restrict__ e, float* __restrict__ acc,
                            const int* __restrict__ tau, int init)
{
    float thr = (float)tau[0];
    for (size_t i = (size_t)blockIdx.x * blockDim.x + threadIdx.x; i < NE;
         i += (size_t)gridDim.x * blockDim.x) {
        float al = 1.0f / (1.0f + expf(-logits[i]));
        float lm = (al > thr) ? 1.0f : 0.0f;
        float vm = (al < 1.0f - thr) ? 1.0f : 0.0f;
        float v = al * lm * a[i] + (1.0f - al) * vm * e[i];
        acc[i] = init ? v : (acc[i] + v);
    }
}

// ---------------- aq = acc / sqrt(3) * maskq[row] -----------------------------------
__global__ void scale_mask_kernel(float* __restrict__ acc, const float* __restrict__ maskq)
{
    for (size_t i = (size_t)blockIdx.x * blockDim.x + threadIdx.x; i < NE;
         i += (size_t)gridDim.x * blockDim.x) {
        acc[i] = acc[i] * 0.57735026918962576f * maskq[i / EE];
    }
}

extern "C" void kernel_launch(void* const* d_in, const int* in_sizes, int n_in,
                              void* d_out, int out_size, void* d_ws, size_t ws_size,
                              hipStream_t stream)
{
    const float* x        = (const float*)d_in[0];
    const float* enc      = (const float*)d_in[1];
    const float* maskq    = (const float*)d_in[2];
    const int*   mask_enc = (const int*)d_in[4];
    const int*   tau      = (const int*)d_in[6];
    const float* Wq = (const float*)d_in[7];
    const float* Wk = (const float*)d_in[8];
    const float* Wv = (const float*)d_in[9];
    const float* Wo = (const float*)d_in[10];
    const float* bo = (const float*)d_in[11];
    const float* fcq_w = (const float*)d_in[12];
    const float* fcq_b = (const float*)d_in[13];
    const float* fck_w = (const float*)d_in[14];
    const float* fck_b = (const float*)d_in[15];
    const float* fcv_w = (const float*)d_in[16];
    const float* fcv_b = (const float*)d_in[17];
    const float* cproj_w = (const float*)d_in[18];
    const float* cproj_b = (const float*)d_in[19];
    const float* ln1_g = (const float*)d_in[20];
    const float* ln1_b = (const float*)d_in[21];
    const float* ln2_g = (const float*)d_in[22];
    const float* ln2_b = (const float*)d_in[23];
    const float* cfc_w = (const float*)d_in[24];
    const float* cfc_b = (const float*)d_in[25];
    const float* cproj2_w = (const float*)d_in[26];
    const float* cproj2_b = (const float*)d_in[27];
    const float* aw[3] = {(const float*)d_in[28], (const float*)d_in[30], (const float*)d_in[32]};
    const float* ab[3] = {(const float*)d_in[29], (const float*)d_in[31], (const float*)d_in[33]};

    float* out   = (float*)d_out;       // [NTOK, E]
    float* kpres = out + NE;            // present[0]: [B,H,S,D]
    float* vpres = out + 2 * NE;        // present[1]

    float* ws     = (float*)d_ws;
    float* xl     = ws;                 // also: el, e-proj temp, aqln
    float* qb     = ws + 1 * NE;        // self q, then cross q  [B,H,S,D]
    float* attout = ws + 2 * NE;        // attention output [N,E]
    float* a      = ws + 3 * NE;
    float* al     = ws + 4 * NE;
    float* kc     = ws + 5 * NE;        // cross K [B,H,S,D]
    float* vc     = ws + 6 * NE;        // cross V
    float* acc    = ws + 7 * NE;        // gated sum -> aq
    float* ebuf   = ws + 8 * NE;        // e_idx
    float* mlph   = ws + 9 * NE;        // [N, F]
    float* alpha  = out;                // transient gate-logit scratch (overwritten by final GEMM)

    dim3 blk(256);
    dim3 gE(NTOK / GBM, EE / GBN);      // 32 x 12
    dim3 gF(NTOK / GBM, FF / GBN);      // 32 x 48
    dim3 gAttn(SS / QT, BB * HH);       // 8 x 96

    // 1. xl = ln1(x)
    ln_kernel<<<NTOK, blk, 0, stream>>>(x, xl, ln1_g, ln1_b, 0, (size_t)SS * EE);
    // 2. self q,k,v (k,v straight into present region of d_out)
    gemm_kernel<<<gE, blk, 0, stream>>>(xl, Wq, nullptr, qb,    nullptr, nullptr, NTOK, EE, EE, FLAG_BHSD);
    gemm_kernel<<<gE, blk, 0, stream>>>(xl, Wk, nullptr, kpres, nullptr, nullptr, NTOK, EE, EE, FLAG_BHSD);
    gemm_kernel<<<gE, blk, 0, stream>>>(xl, Wv, nullptr, vpres, nullptr, nullptr, NTOK, EE, EE, FLAG_BHSD);
    // 3. causal self-attention
    fattn_kernel<<<gAttn, blk, 0, stream>>>(qb, kpres, vpres, nullptr, attout, 1);
    // 4. a = attout@Wo + bo + x
    gemm_kernel<<<gE, blk, 0, stream>>>(attout, Wo, bo, a, x, nullptr, NTOK, EE, EE, FLAG_RES);
    // 5. al = ln1(a)
    ln_kernel<<<NTOK, blk, 0, stream>>>(a, al, ln1_g, ln1_b, 0, (size_t)SS * EE);
    // 6. cross q (shared across the 3 encoders)
    gemm_kernel<<<gE, blk, 0, stream>>>(al, fcq_w, fcq_b, qb, nullptr, nullptr, NTOK, EE, EE, FLAG_BHSD);
    // 7. three cross-attention branches + gates
    for (int idx = 0; idx < 3; ++idx) {
        ln_kernel<<<NTOK, blk, 0, stream>>>(enc, xl, ln1_g, ln1_b,
                                            (size_t)idx * SS * EE, (size_t)3 * SS * EE);
        gemm_kernel<<<gE, blk, 0, stream>>>(xl, fck_w, fck_b, kc, nullptr, nullptr, NTOK, EE, EE, FLAG_BHSD);
        gemm_kernel<<<gE, blk, 0, stream>>>(xl, fcv_w, fcv_b, vc, nullptr, nullptr, NTOK, EE, EE, FLAG_BHSD);
        fattn_kernel<<<gAttn, blk, 0, stream>>>(qb, kc, vc, mask_enc, attout, 0);
        gemm_kernel<<<gE, blk, 0, stream>>>(attout, cproj_w, cproj_b, ebuf, nullptr, nullptr, NTOK, EE, EE, 0);
        // gate logits: a @ aw[0:768] + e @ aw[768:1536] + ab
        gemm_kernel<<<gE, blk, 0, stream>>>(a,    aw[idx],             ab[idx], alpha, nullptr, nullptr, NTOK, EE, EE, 0);
        gemm_kernel<<<gE, blk, 0, stream>>>(ebuf, aw[idx] + 768 * 768, nullptr, alpha, nullptr, nullptr, NTOK, EE, EE, FLAG_ACC);
        gate_kernel<<<2048, blk, 0, stream>>>(alpha, a, ebuf, acc, tau, idx == 0 ? 1 : 0);
    }
    // 8. aq = acc / sqrt3 * maskq   (in place)
    scale_mask_kernel<<<2048, blk, 0, stream>>>(acc, maskq);
    // 9. aqln = ln2(aq)
    ln_kernel<<<NTOK, blk, 0, stream>>>(acc, xl, ln2_g, ln2_b, 0, (size_t)SS * EE);
    // 10. mlph = gelu(aqln @ cfc + cfc_b)
    gemm_kernel<<<gF, blk, 0, stream>>>(xl, cfc_w, cfc_b, mlph, nullptr, nullptr, NTOK, FF, EE, FLAG_GELU);
    // 11. out = (aq + mlph @ cproj2 + cproj2_b) * maskq
    gemm_kernel<<<gE, blk, 0, stream>>>(mlph, cproj2_w, cproj2_b, out, acc, maskq, NTOK, EE, FF, FLAG_FIN);
}

// Round 5
// 1565.210 us; speedup vs baseline: 4.1747x; 2.1166x over previous
//
#include <hip/hip_runtime.h>
#include <hip/hip_bf16.h>
#include <math.h>

typedef __hip_bfloat16 bf16;
typedef __attribute__((ext_vector_type(8))) short s16x8;
typedef __attribute__((ext_vector_type(4))) float f32x4;

// Problem constants
#define BB 8
#define SS 512
#define EE 768
#define HH 12
#define DD 64
#define FF 3072
#define NTOK (BB * SS)            // 4096 tokens
#define NE ((size_t)NTOK * EE)    // 3,145,728

// MFMA GEMM tile
#define TM 128
#define TN 128
#define TK 64

// attention tiles
#define QT 64
#define KT 64

// flags
#define FLAG_BHSD 2   // store permuted to [B,H,S,D]
#define FLAG_RES  4   // + Rsrc[row,col]
#define FLAG_GELU 8   // gelu_new epilogue
#define FLAG_FIN  16  // out = (Rsrc + v) * maskq[row]

__device__ __forceinline__ float gelu_new(float x) {
    return 0.5f * x * (1.0f + tanhf(0.7978845608028654f * (x + 0.044715f * x * x * x)));
}

// ---------------- weight transpose+cast: src f32 [R][C] -> dst bf16 [C][R] ----------
__global__ __launch_bounds__(256) void tcast_kernel(
    const float* __restrict__ src, bf16* __restrict__ dst, int R, int C)
{
    __shared__ float t[32][33];
    int c0 = blockIdx.x * 32, r0 = blockIdx.y * 32;
    int tid = threadIdx.x;
    int x = tid & 31, y = tid >> 5;     // 32 cols x 8 rows per pass
    #pragma unroll
    for (int i = 0; i < 4; ++i) {
        int r = y + i * 8;
        t[r][x] = src[(size_t)(r0 + r) * C + c0 + x];
    }
    __syncthreads();
    #pragma unroll
    for (int i = 0; i < 4; ++i) {
        int c = y + i * 8;
        dst[(size_t)(c0 + c) * R + r0 + x] = __float2bfloat16(t[x][c]);
    }
}

// ---------------- LayerNorm: one block per row; bf16 output -------------------------
__global__ __launch_bounds__(256) void ln_kernel(
    const float* __restrict__ in, bf16* __restrict__ out,
    const float* __restrict__ g, const float* __restrict__ bta,
    size_t base_off, size_t batch_stride)
{
    int row = blockIdx.x;               // 0..NTOK-1
    int b = row >> 9, s = row & 511;
    const float* x = in + base_off + (size_t)b * batch_stride + (size_t)s * EE;
    int tid = threadIdx.x;

    float v0 = x[tid], v1 = x[tid + 256], v2 = x[tid + 512];
    float s1 = v0 + v1 + v2;
    float s2 = v0 * v0 + v1 * v1 + v2 * v2;
    #pragma unroll
    for (int o = 32; o > 0; o >>= 1) {
        s1 += __shfl_down(s1, o);
        s2 += __shfl_down(s2, o);
    }
    __shared__ float r1[4], r2[4];
    if ((tid & 63) == 0) { r1[tid >> 6] = s1; r2[tid >> 6] = s2; }
    __syncthreads();
    float mean = (r1[0] + r1[1] + r1[2] + r1[3]) * (1.0f / 768.0f);
    float ssq  = (r2[0] + r2[1] + r2[2] + r2[3]) * (1.0f / 768.0f);
    float var = ssq - mean * mean;
    float rstd = rsqrtf(var + 1e-5f);

    bf16* y = out + (size_t)row * EE;
    y[tid]       = __float2bfloat16((v0 - mean) * rstd * g[tid]       + bta[tid]);
    y[tid + 256] = __float2bfloat16((v1 - mean) * rstd * g[tid + 256] + bta[tid + 256]);
    y[tid + 512] = __float2bfloat16((v2 - mean) * rstd * g[tid + 512] + bta[tid + 512]);
}

// ---------------- bf16 MFMA GEMM: C[M,Nn] = A[M,K](bf16) @ Wt[Nn,K]^T (bf16) --------
// 128x128 tile, BK=64, 4 waves in 2x2 quadrants, 4x4 frags of 16x16x32 MFMA.
// A-frag lane l: A[idx = l&15][k = (l>>4)*8 .. +7]; same structure for B (Wt rows).
// C/D: row = (l>>4)*4 + reg, col = l&15  [verified m89/m225].
__global__ __launch_bounds__(256) void mgemm_kernel(
    const bf16* __restrict__ A, const bf16* __restrict__ Wt,
    const float* __restrict__ bias, float* __restrict__ Cf,
    bf16* __restrict__ Cb, int ldcb,
    const float* __restrict__ Rsrc, const float* __restrict__ maskq,
    int Nn, int K, int lda, int flags)
{
    __shared__ __align__(16) bf16 As[TM][TK];   // 16 KB
    __shared__ __align__(16) bf16 Bs[TN][TK];   // 16 KB
    int tid = threadIdx.x;
    int w = tid >> 6, l = tid & 63;
    int row0 = blockIdx.x * TM, col0 = blockIdx.y * TN;
    int wr = (w >> 1) * 64, wc = (w & 1) * 64;  // wave quadrant origin
    int lr = l & 15, lg = l >> 4;

    f32x4 acc[4][4];
    #pragma unroll
    for (int m = 0; m < 4; ++m)
        #pragma unroll
        for (int n = 0; n < 4; ++n) acc[m][n] = (f32x4){0.f, 0.f, 0.f, 0.f};

    for (int kb = 0; kb < K; kb += TK) {
        // ---- stage A,B tiles: 4 x global_load_lds(16B) each, linear LDS ----
        #pragma unroll
        for (int i = 0; i < 4; ++i) {
            int e = (i * 256 + tid) * 8;        // element offset in 128x64 tile
            int r = e >> 6, c = e & 63;
            __builtin_amdgcn_global_load_lds(
                (const __attribute__((address_space(1))) void*)(A + (size_t)(row0 + r) * lda + kb + c),
                (__attribute__((address_space(3))) void*)((char*)&As[0][0] + i * 4096 + w * 1024),
                16, 0, 0);
            __builtin_amdgcn_global_load_lds(
                (const __attribute__((address_space(1))) void*)(Wt + (size_t)(col0 + r) * K + kb + c),
                (__attribute__((address_space(3))) void*)((char*)&Bs[0][0] + i * 4096 + w * 1024),
                16, 0, 0);
        }
        __syncthreads();
        // ---- 2 k-steps of 32; 16 MFMA each ----
        #pragma unroll
        for (int ks = 0; ks < 2; ++ks) {
            s16x8 af[4], bfr[4];
            #pragma unroll
            for (int m = 0; m < 4; ++m)
                af[m] = *(const s16x8*)&As[wr + m * 16 + lr][ks * 32 + lg * 8];
            #pragma unroll
            for (int n = 0; n < 4; ++n)
                bfr[n] = *(const s16x8*)&Bs[wc + n * 16 + lr][ks * 32 + lg * 8];
            #pragma unroll
            for (int m = 0; m < 4; ++m)
                #pragma unroll
                for (int n = 0; n < 4; ++n)
                    acc[m][n] = __builtin_amdgcn_mfma_f32_16x16x32_bf16(
                        af[m], bfr[n], acc[m][n], 0, 0, 0);
        }
        __syncthreads();
    }

    bool f_bhsd = flags & FLAG_BHSD;
    bool f_res  = flags & FLAG_RES;
    bool f_gelu = flags & FLAG_GELU;
    bool f_fin  = flags & FLAG_FIN;

    #pragma unroll
    for (int m = 0; m < 4; ++m) {
        #pragma unroll
        for (int n = 0; n < 4; ++n) {
            #pragma unroll
            for (int j = 0; j < 4; ++j) {
                int row = row0 + wr + m * 16 + lg * 4 + j;
                int col = col0 + wc + n * 16 + lr;
                size_t lin = (size_t)row * Nn + col;
                float v = acc[m][n][j];
                if (bias)   v += bias[col];
                if (f_res)  v += Rsrc[lin];
                if (f_gelu) v = gelu_new(v);
                if (f_fin)  v = (Rsrc[lin] + v) * maskq[row];
                if (f_bhsd) {
                    int b = row >> 9, s = row & 511;
                    int h = col >> 6, d = col & 63;
                    Cf[(((size_t)b * HH + h) * SS + s) * DD + d] = v;
                } else if (Cf) {
                    Cf[lin] = v;
                }
                if (Cb) Cb[(size_t)row * ldcb + col] = __float2bfloat16(v);
            }
        }
    }
}

// ---------------- tiled flash attention (f32 math, bf16 output) ---------------------
__global__ __launch_bounds__(256) void fattn_kernel(
    const float* __restrict__ Q, const float* __restrict__ Kt,
    const float* __restrict__ Vt, const int* __restrict__ maskE,
    bf16* __restrict__ Out, int causal)
{
    int qt = blockIdx.x, bh = blockIdx.y;
    int b = bh / HH, h = bh % HH;
    int tid = threadIdx.x;
    int q = tid & 63;
    int slot = tid >> 6;

    __shared__ float Ks[KT][DD];
    __shared__ float Vs[KT][DD];
    __shared__ float Ps[QT][KT + 2];
    __shared__ float rowred[QT][4];
    __shared__ int   kmask[KT];

    float qreg[DD];
    {
        const float4* qrow = (const float4*)(Q + ((size_t)bh * SS + qt * QT + q) * DD);
        #pragma unroll
        for (int i = 0; i < DD / 4; ++i) {
            float4 v = qrow[i];
            qreg[i*4+0] = v.x; qreg[i*4+1] = v.y; qreg[i*4+2] = v.z; qreg[i*4+3] = v.w;
        }
    }

    float m = -3.0e38f, lsum = 0.f;
    float o[16];
    #pragma unroll
    for (int i = 0; i < 16; ++i) o[i] = 0.f;

    int q_glob = qt * QT + q;
    int ntiles = causal ? (qt + 1) : (SS / KT);

    for (int kt = 0; kt < ntiles; ++kt) {
        const float* Kg = Kt + ((size_t)bh * SS + kt * KT) * DD;
        const float* Vg = Vt + ((size_t)bh * SS + kt * KT) * DD;
        #pragma unroll
        for (int i = 0; i < 4; ++i) {
            int idx = tid + i * 256;
            int r = idx >> 4, c = idx & 15;
            *(float4*)&Ks[r][c * 4] = *(const float4*)&Kg[(size_t)r * DD + c * 4];
            *(float4*)&Vs[r][c * 4] = *(const float4*)&Vg[(size_t)r * DD + c * 4];
        }
        if (maskE && tid < KT) kmask[tid] = maskE[(size_t)b * SS + kt * KT + tid];
        __syncthreads();

        float s[16];
        #pragma unroll
        for (int j = 0; j < 16; ++j) {
            int k = slot * 16 + j;
            float a = 0.f;
            #pragma unroll
            for (int d4 = 0; d4 < 16; ++d4) {
                float4 kv = *(const float4*)&Ks[k][d4 * 4];
                a += kv.x * qreg[d4*4]   + kv.y * qreg[d4*4+1]
                   + kv.z * qreg[d4*4+2] + kv.w * qreg[d4*4+3];
            }
            a *= 0.125f;
            if (causal) {
                if (kt * KT + k > q_glob) a = -3.0e38f;
            } else {
                if (kmask[k] != 0) a = -1e4f;
            }
            s[j] = a;
        }
        float lm = s[0];
        #pragma unroll
        for (int j = 1; j < 16; ++j) lm = fmaxf(lm, s[j]);
        rowred[q][slot] = lm;
        __syncthreads();
        float tmax = fmaxf(fmaxf(rowred[q][0], rowred[q][1]),
                           fmaxf(rowred[q][2], rowred[q][3]));
        float mnew = fmaxf(m, tmax);
        float resc = expf(m - mnew);
        m = mnew;
        lsum *= resc;
        #pragma unroll
        for (int i = 0; i < 16; ++i) o[i] *= resc;
        float psum = 0.f;
        #pragma unroll
        for (int j = 0; j < 16; ++j) {
            float p = expf(s[j] - m);
            psum += p;
            Ps[q][slot * 16 + j] = p;
        }
        lsum += psum;
        __syncthreads();

        for (int k = 0; k < KT; ++k) {
            float p = Ps[q][k];
            #pragma unroll
            for (int d4 = 0; d4 < 4; ++d4) {
                float4 v = *(const float4*)&Vs[k][slot * 16 + d4 * 4];
                o[d4*4+0] += p * v.x; o[d4*4+1] += p * v.y;
                o[d4*4+2] += p * v.z; o[d4*4+3] += p * v.w;
            }
        }
        __syncthreads();
    }

    rowred[q][slot] = lsum;
    __syncthreads();
    float inv = 1.0f / (rowred[q][0] + rowred[q][1] + rowred[q][2] + rowred[q][3]);
    bf16* op = Out + ((size_t)b * SS + q_glob) * EE + h * DD + slot * 16;
    #pragma unroll
    for (int i = 0; i < 16; ++i) op[i] = __float2bfloat16(o[i] * inv);
}

// ---------------- gate: acc (+)= alpha*lm*a + (1-alpha)*vm*e ------------------------
__global__ void gate_kernel(const float* __restrict__ logits, const float* __restrict__ a,
                            const float* __restrict__ e, float* __restrict__ acc,
                            const int* __restrict__ tau, int init)
{
    float thr = (float)tau[0];
    for (size_t i = (size_t)blockIdx.x * blockDim.x + threadIdx.x; i < NE;
         i += (size_t)gridDim.x * blockDim.x) {
        float al = 1.0f / (1.0f + expf(-logits[i]));
        float lm = (al > thr) ? 1.0f : 0.0f;
        float vm = (al < 1.0f - thr) ? 1.0f : 0.0f;
        float v = al * lm * a[i] + (1.0f - al) * vm * e[i];
        acc[i] = init ? v : (acc[i] + v);
    }
}

// ---------------- aq = acc / sqrt(3) * maskq[row] -----------------------------------
__global__ void scale_mask_kernel(float* __restrict__ acc, const float* __restrict__ maskq)
{
    for (size_t i = (size_t)blockIdx.x * blockDim.x + threadIdx.x; i < NE;
         i += (size_t)gridDim.x * blockDim.x) {
        acc[i] = acc[i] * 0.57735026918962576f * maskq[i / EE];
    }
}

extern "C" void kernel_launch(void* const* d_in, const int* in_sizes, int n_in,
                              void* d_out, int out_size, void* d_ws, size_t ws_size,
                              hipStream_t stream)
{
    const float* x        = (const float*)d_in[0];
    const float* enc      = (const float*)d_in[1];
    const float* maskq    = (const float*)d_in[2];
    const int*   mask_enc = (const int*)d_in[4];
    const int*   tau      = (const int*)d_in[6];
    const float* Wq = (const float*)d_in[7];
    const float* Wk = (const float*)d_in[8];
    const float* Wv = (const float*)d_in[9];
    const float* Wo = (const float*)d_in[10];
    const float* bo = (const float*)d_in[11];
    const float* fcq_w = (const float*)d_in[12];
    const float* fcq_b = (const float*)d_in[13];
    const float* fck_w = (const float*)d_in[14];
    const float* fck_b = (const float*)d_in[15];
    const float* fcv_w = (const float*)d_in[16];
    const float* fcv_b = (const float*)d_in[17];
    const float* cproj_w = (const float*)d_in[18];
    const float* cproj_b = (const float*)d_in[19];
    const float* ln1_g = (const float*)d_in[20];
    const float* ln1_b = (const float*)d_in[21];
    const float* ln2_g = (const float*)d_in[22];
    const float* ln2_b = (const float*)d_in[23];
    const float* cfc_w = (const float*)d_in[24];
    const float* cfc_b = (const float*)d_in[25];
    const float* cproj2_w = (const float*)d_in[26];
    const float* cproj2_b = (const float*)d_in[27];
    const float* aw[3] = {(const float*)d_in[28], (const float*)d_in[30], (const float*)d_in[32]};
    const float* ab[3] = {(const float*)d_in[29], (const float*)d_in[31], (const float*)d_in[33]};

    float* out   = (float*)d_out;       // [NTOK, E]
    float* kpres = out + NE;            // present[0]: [B,H,S,D] f32
    float* vpres = out + 2 * NE;        // present[1]

    float* ws   = (float*)d_ws;
    float* qb   = ws + 0 * NE;          // q (self, then cross) [B,H,S,D] f32
    float* a    = ws + 1 * NE;          // residual after self-attn, f32
    float* ebuf = ws + 2 * NE;          // cross-attn branch output, f32
    float* acc  = ws + 3 * NE;          // gated sum -> aq, f32
    float* kc   = ws + 4 * NE;          // cross K [B,H,S,D] f32
    float* vc   = ws + 5 * NE;          // cross V
    bf16* lnb     = (bf16*)(ws + 6 * NE);               // LN outputs (xl/al/el/aqln)
    bf16* attoutb = (bf16*)(ws + 6 * NE + NE / 2);      // attention out, bf16
    bf16* abf     = (bf16*)(ws + 7 * NE);               // [NTOK][1536] = a_bf16 | e_bf16
    bf16* mlphb   = (bf16*)(ws + 8 * NE);               // [NTOK][3072] bf16
    bf16* wp      = (bf16*)(ws + 10 * NE);              // transposed bf16 weights
    bf16* WqT = wp;            wp += 768 * 768;
    bf16* WkT = wp;            wp += 768 * 768;
    bf16* WvT = wp;            wp += 768 * 768;
    bf16* WoT = wp;            wp += 768 * 768;
    bf16* fcqT = wp;           wp += 768 * 768;
    bf16* fckT = wp;           wp += 768 * 768;
    bf16* fcvT = wp;           wp += 768 * 768;
    bf16* cprojT = wp;         wp += 768 * 768;
    bf16* awT[3];
    awT[0] = wp;               wp += 1536 * 768;
    awT[1] = wp;               wp += 1536 * 768;
    awT[2] = wp;               wp += 1536 * 768;
    bf16* cfcT = wp;           wp += (size_t)768 * 3072;   // [3072][768]
    bf16* cproj2T = wp;        wp += (size_t)3072 * 768;   // [768][3072]
    float* alpha = out;        // transient gate-logit scratch (overwritten by final GEMM)

    dim3 blk(256);
    dim3 gE(NTOK / TM, EE / TN);        // 32 x 6
    dim3 gF(NTOK / TM, FF / TN);        // 32 x 24
    dim3 gAttn(SS / QT, BB * HH);       // 8 x 96
    dim3 gT88(768 / 32, 768 / 32);
    dim3 gTaw(768 / 32, 1536 / 32);
    dim3 gTcf(3072 / 32, 768 / 32);
    dim3 gTcp(768 / 32, 3072 / 32);

    // 0. weight transpose+cast to bf16 [N][K]
    tcast_kernel<<<gT88, blk, 0, stream>>>(Wq, WqT, 768, 768);
    tcast_kernel<<<gT88, blk, 0, stream>>>(Wk, WkT, 768, 768);
    tcast_kernel<<<gT88, blk, 0, stream>>>(Wv, WvT, 768, 768);
    tcast_kernel<<<gT88, blk, 0, stream>>>(Wo, WoT, 768, 768);
    tcast_kernel<<<gT88, blk, 0, stream>>>(fcq_w, fcqT, 768, 768);
    tcast_kernel<<<gT88, blk, 0, stream>>>(fck_w, fckT, 768, 768);
    tcast_kernel<<<gT88, blk, 0, stream>>>(fcv_w, fcvT, 768, 768);
    tcast_kernel<<<gT88, blk, 0, stream>>>(cproj_w, cprojT, 768, 768);
    tcast_kernel<<<gTaw, blk, 0, stream>>>(aw[0], awT[0], 1536, 768);
    tcast_kernel<<<gTaw, blk, 0, stream>>>(aw[1], awT[1], 1536, 768);
    tcast_kernel<<<gTaw, blk, 0, stream>>>(aw[2], awT[2], 1536, 768);
    tcast_kernel<<<gTcf, blk, 0, stream>>>(cfc_w, cfcT, 768, 3072);
    tcast_kernel<<<gTcp, blk, 0, stream>>>(cproj2_w, cproj2T, 3072, 768);

    // 1. xl = ln1(x) -> lnb (bf16)
    ln_kernel<<<NTOK, blk, 0, stream>>>(x, lnb, ln1_g, ln1_b, 0, (size_t)SS * EE);
    // 2. self q,k,v (k,v straight into present region of d_out, f32 BHSD)
    mgemm_kernel<<<gE, blk, 0, stream>>>(lnb, WqT, nullptr, qb,    nullptr, 0, nullptr, nullptr, EE, EE, EE, FLAG_BHSD);
    mgemm_kernel<<<gE, blk, 0, stream>>>(lnb, WkT, nullptr, kpres, nullptr, 0, nullptr, nullptr, EE, EE, EE, FLAG_BHSD);
    mgemm_kernel<<<gE, blk, 0, stream>>>(lnb, WvT, nullptr, vpres, nullptr, 0, nullptr, nullptr, EE, EE, EE, FLAG_BHSD);
    // 3. causal self-attention -> attoutb (bf16)
    fattn_kernel<<<gAttn, blk, 0, stream>>>(qb, kpres, vpres, nullptr, attoutb, 1);
    // 4. a = attout@Wo + bo + x (f32), dual bf16 into abf[:, 0:768]
    mgemm_kernel<<<gE, blk, 0, stream>>>(attoutb, WoT, bo, a, abf, 1536, x, nullptr, EE, EE, EE, FLAG_RES);
    // 5. al = ln1(a) -> lnb
    ln_kernel<<<NTOK, blk, 0, stream>>>(a, lnb, ln1_g, ln1_b, 0, (size_t)SS * EE);
    // 6. cross q (shared across the 3 encoders)
    mgemm_kernel<<<gE, blk, 0, stream>>>(lnb, fcqT, fcq_b, qb, nullptr, 0, nullptr, nullptr, EE, EE, EE, FLAG_BHSD);
    // 7. three cross-attention branches + gates
    for (int idx = 0; idx < 3; ++idx) {
        ln_kernel<<<NTOK, blk, 0, stream>>>(enc, lnb, ln1_g, ln1_b,
                                            (size_t)idx * SS * EE, (size_t)3 * SS * EE);
        mgemm_kernel<<<gE, blk, 0, stream>>>(lnb, fckT, fck_b, kc, nullptr, 0, nullptr, nullptr, EE, EE, EE, FLAG_BHSD);
        mgemm_kernel<<<gE, blk, 0, stream>>>(lnb, fcvT, fcv_b, vc, nullptr, 0, nullptr, nullptr, EE, EE, EE, FLAG_BHSD);
        fattn_kernel<<<gAttn, blk, 0, stream>>>(qb, kc, vc, mask_enc, attoutb, 0);
        // e = attout@cproj + b  (f32 ebuf for gate elementwise, bf16 into abf[:, 768:1536])
        mgemm_kernel<<<gE, blk, 0, stream>>>(attoutb, cprojT, cproj_b, ebuf, abf + 768, 1536, nullptr, nullptr, EE, EE, EE, 0);
        // gate logits: [a,e] @ aw + ab, single K=1536 GEMM
        mgemm_kernel<<<gE, blk, 0, stream>>>(abf, awT[idx], ab[idx], alpha, nullptr, 0, nullptr, nullptr, EE, 1536, 1536, 0);
        gate_kernel<<<2048, blk, 0, stream>>>(alpha, a, ebuf, acc, tau, idx == 0 ? 1 : 0);
    }
    // 8. aq = acc / sqrt3 * maskq   (in place)
    scale_mask_kernel<<<2048, blk, 0, stream>>>(acc, maskq);
    // 9. aqln = ln2(aq) -> lnb
    ln_kernel<<<NTOK, blk, 0, stream>>>(acc, lnb, ln2_g, ln2_b, 0, (size_t)SS * EE);
    // 10. mlph = gelu(aqln @ cfc + cfc_b) -> bf16 only
    mgemm_kernel<<<gF, blk, 0, stream>>>(lnb, cfcT, cfc_b, nullptr, mlphb, FF, nullptr, nullptr, FF, EE, EE, FLAG_GELU);
    // 11. out = (aq + mlph @ cproj2 + cproj2_b) * maskq
    mgemm_kernel<<<gE, blk, 0, stream>>>(mlphb, cproj2T, cproj2_b, out, nullptr, 0, acc, maskq, EE, FF, FF, FLAG_FIN);
}

// Round 6
// 1006.536 us; speedup vs baseline: 6.4918x; 1.5550x over previous
//
#include <hip/hip_runtime.h>
#include <hip/hip_bf16.h>
#include <math.h>

typedef __hip_bfloat16 bf16;
typedef __attribute__((ext_vector_type(8))) short s16x8;
typedef __attribute__((ext_vector_type(4))) float f32x4;

// Problem constants
#define BB 8
#define SS 512
#define EE 768
#define HH 12
#define DD 64
#define FF 3072
#define NTOK (BB * SS)            // 4096 tokens
#define NE ((size_t)NTOK * EE)    // 3,145,728

// MFMA GEMM tile
#define TM 128
#define TN 128
#define TK 64

// attention tiles
#define QT 64
#define KT 64

// flags
#define FLAG_BHSD 2   // Cf store permuted to [B,H,S,D]
#define FLAG_RES  4   // + Rsrc[row,col]
#define FLAG_GELU 8   // gelu_new epilogue
#define FLAG_FIN  16  // out = (Rsrc + v) * maskq[row]
#define FLAG_CBSD 32  // Cb store [B,H,S,D] bf16
#define FLAG_CBDS 64  // Cb store [B,H,D,S] bf16 (transposed per head)

__device__ __forceinline__ float gelu_new(float x) {
    return 0.5f * x * (1.0f + tanhf(0.7978845608028654f * (x + 0.044715f * x * x * x)));
}

// ---------------- weight transpose+cast: src f32 [R][C] -> dst bf16 [C][R] ----------
__global__ __launch_bounds__(256) void tcast_kernel(
    const float* __restrict__ src, bf16* __restrict__ dst, int R, int C)
{
    __shared__ float t[32][33];
    int c0 = blockIdx.x * 32, r0 = blockIdx.y * 32;
    int tid = threadIdx.x;
    int x = tid & 31, y = tid >> 5;
    #pragma unroll
    for (int i = 0; i < 4; ++i) {
        int r = y + i * 8;
        t[r][x] = src[(size_t)(r0 + r) * C + c0 + x];
    }
    __syncthreads();
    #pragma unroll
    for (int i = 0; i < 4; ++i) {
        int c = y + i * 8;
        dst[(size_t)(c0 + c) * R + r0 + x] = __float2bfloat16(t[x][c]);
    }
}

// ---------------- LayerNorm: one block per row; bf16 output -------------------------
__global__ __launch_bounds__(256) void ln_kernel(
    const float* __restrict__ in, bf16* __restrict__ out,
    const float* __restrict__ g, const float* __restrict__ bta,
    size_t base_off, size_t batch_stride)
{
    int row = blockIdx.x;
    int b = row >> 9, s = row & 511;
    const float* x = in + base_off + (size_t)b * batch_stride + (size_t)s * EE;
    int tid = threadIdx.x;

    float v0 = x[tid], v1 = x[tid + 256], v2 = x[tid + 512];
    float s1 = v0 + v1 + v2;
    float s2 = v0 * v0 + v1 * v1 + v2 * v2;
    #pragma unroll
    for (int o = 32; o > 0; o >>= 1) {
        s1 += __shfl_down(s1, o);
        s2 += __shfl_down(s2, o);
    }
    __shared__ float r1[4], r2[4];
    if ((tid & 63) == 0) { r1[tid >> 6] = s1; r2[tid >> 6] = s2; }
    __syncthreads();
    float mean = (r1[0] + r1[1] + r1[2] + r1[3]) * (1.0f / 768.0f);
    float ssq  = (r2[0] + r2[1] + r2[2] + r2[3]) * (1.0f / 768.0f);
    float var = ssq - mean * mean;
    float rstd = rsqrtf(var + 1e-5f);

    bf16* y = out + (size_t)row * EE;
    y[tid]       = __float2bfloat16((v0 - mean) * rstd * g[tid]       + bta[tid]);
    y[tid + 256] = __float2bfloat16((v1 - mean) * rstd * g[tid + 256] + bta[tid + 256]);
    y[tid + 512] = __float2bfloat16((v2 - mean) * rstd * g[tid + 512] + bta[tid + 512]);
}

// ---------------- bf16 MFMA GEMM (validated frag layouts) ---------------------------
__global__ __launch_bounds__(256) void mgemm_kernel(
    const bf16* __restrict__ A, const bf16* __restrict__ Wt,
    const float* __restrict__ bias, float* __restrict__ Cf,
    bf16* __restrict__ Cb, int ldcb,
    const float* __restrict__ Rsrc, const float* __restrict__ maskq,
    int Nn, int K, int lda, int flags)
{
    __shared__ __align__(16) bf16 As[TM][TK];
    __shared__ __align__(16) bf16 Bs[TN][TK];
    int tid = threadIdx.x;
    int w = tid >> 6, l = tid & 63;
    int row0 = blockIdx.x * TM, col0 = blockIdx.y * TN;
    int wr = (w >> 1) * 64, wc = (w & 1) * 64;
    int lr = l & 15, lg = l >> 4;

    f32x4 acc[4][4];
    #pragma unroll
    for (int m = 0; m < 4; ++m)
        #pragma unroll
        for (int n = 0; n < 4; ++n) acc[m][n] = (f32x4){0.f, 0.f, 0.f, 0.f};

    for (int kb = 0; kb < K; kb += TK) {
        #pragma unroll
        for (int i = 0; i < 4; ++i) {
            int e = (i * 256 + tid) * 8;
            int r = e >> 6, c = e & 63;
            __builtin_amdgcn_global_load_lds(
                (const __attribute__((address_space(1))) void*)(A + (size_t)(row0 + r) * lda + kb + c),
                (__attribute__((address_space(3))) void*)((char*)&As[0][0] + i * 4096 + w * 1024),
                16, 0, 0);
            __builtin_amdgcn_global_load_lds(
                (const __attribute__((address_space(1))) void*)(Wt + (size_t)(col0 + r) * K + kb + c),
                (__attribute__((address_space(3))) void*)((char*)&Bs[0][0] + i * 4096 + w * 1024),
                16, 0, 0);
        }
        __syncthreads();
        #pragma unroll
        for (int ks = 0; ks < 2; ++ks) {
            s16x8 af[4], bfr[4];
            #pragma unroll
            for (int m = 0; m < 4; ++m)
                af[m] = *(const s16x8*)&As[wr + m * 16 + lr][ks * 32 + lg * 8];
            #pragma unroll
            for (int n = 0; n < 4; ++n)
                bfr[n] = *(const s16x8*)&Bs[wc + n * 16 + lr][ks * 32 + lg * 8];
            #pragma unroll
            for (int m = 0; m < 4; ++m)
                #pragma unroll
                for (int n = 0; n < 4; ++n)
                    acc[m][n] = __builtin_amdgcn_mfma_f32_16x16x32_bf16(
                        af[m], bfr[n], acc[m][n], 0, 0, 0);
        }
        __syncthreads();
    }

    bool f_bhsd = flags & FLAG_BHSD;
    bool f_res  = flags & FLAG_RES;
    bool f_gelu = flags & FLAG_GELU;
    bool f_fin  = flags & FLAG_FIN;
    bool f_cbsd = flags & FLAG_CBSD;
    bool f_cbds = flags & FLAG_CBDS;

    #pragma unroll
    for (int m = 0; m < 4; ++m) {
        #pragma unroll
        for (int n = 0; n < 4; ++n) {
            #pragma unroll
            for (int j = 0; j < 4; ++j) {
                int row = row0 + wr + m * 16 + lg * 4 + j;
                int col = col0 + wc + n * 16 + lr;
                size_t lin = (size_t)row * Nn + col;
                float v = acc[m][n][j];
                if (bias)   v += bias[col];
                if (f_res)  v += Rsrc[lin];
                if (f_gelu) v = gelu_new(v);
                if (f_fin)  v = (Rsrc[lin] + v) * maskq[row];
                int b = row >> 9, s = row & 511;
                int h = col >> 6, d = col & 63;
                if (Cf) {
                    if (f_bhsd) Cf[(((size_t)b * HH + h) * SS + s) * DD + d] = v;
                    else        Cf[lin] = v;
                }
                if (Cb) {
                    if (f_cbsd)      Cb[(((size_t)b * HH + h) * SS + s) * DD + d] = __float2bfloat16(v);
                    else if (f_cbds) Cb[(((size_t)b * HH + h) * DD + d) * SS + s] = __float2bfloat16(v);
                    else             Cb[(size_t)row * ldcb + col] = __float2bfloat16(v);
                }
            }
        }
    }
}

// ---------------- bf16 MFMA flash attention ----------------------------------------
// grid (8, 96), 256 thr. Q[B,H,S,D], K[B,H,S,D], V^T[B,H,D,S], all bf16, XOR-swizzled
// LDS staging via pre-swizzled global_load_lds source (rule #21).
__global__ __launch_bounds__(256) void fattn2_kernel(
    const bf16* __restrict__ Qb, const bf16* __restrict__ Kb,
    const bf16* __restrict__ Vb, const int* __restrict__ maskE,
    bf16* __restrict__ Out, int causal)
{
    int qt = blockIdx.x, bh = blockIdx.y;
    int b = bh / HH, h = bh % HH;
    int tid = threadIdx.x;
    int w = tid >> 6, l = tid & 63;
    int lr = l & 15, g = l >> 4;

    __shared__ __align__(16) bf16 Qs[64 * 64];
    __shared__ __align__(16) bf16 Ks[64 * 64];
    __shared__ __align__(16) bf16 Vs[64 * 64];
    __shared__ __align__(16) bf16 Ps[64 * 64];

    // per-lane chunk position for staging (linear LDS dest; swizzled global src)
    int p0 = w * 1024 + l * 16;            // chunk i adds i*4096
    // stage Q once
    {
        const char* qg = (const char*)(Qb + ((size_t)bh * SS + qt * QT) * DD);
        #pragma unroll
        for (int i = 0; i < 2; ++i) {
            int p = i * 4096 + p0;
            int row = p >> 7, cb = p & 127;
            int scb = cb ^ ((row & 7) << 4);
            __builtin_amdgcn_global_load_lds(
                (const __attribute__((address_space(1))) void*)(qg + row * 128 + scb),
                (__attribute__((address_space(3))) void*)((char*)Qs + i * 4096 + w * 1024),
                16, 0, 0);
        }
    }

    float mrun[4], lrun[4];
    f32x4 oacc[4];
    #pragma unroll
    for (int j = 0; j < 4; ++j) { mrun[j] = -3.0e38f; lrun[j] = 0.f; }
    #pragma unroll
    for (int n = 0; n < 4; ++n) oacc[n] = (f32x4){0.f, 0.f, 0.f, 0.f};

    int ntiles = causal ? (qt + 1) : (SS / KT);
    int qrow_base = w * 16;                 // wave's q rows within tile

    for (int kt = 0; kt < ntiles; ++kt) {
        // ---- stage K tile [key][d] and V^T tile [d][key] ----
        const char* kg = (const char*)(Kb + ((size_t)bh * SS + kt * KT) * DD);
        const char* vg = (const char*)(Vb + (size_t)bh * DD * SS + (size_t)kt * KT);
        #pragma unroll
        for (int i = 0; i < 2; ++i) {
            int p = i * 4096 + p0;
            int row = p >> 7, cb = p & 127;
            int scb = cb ^ ((row & 7) << 4);
            __builtin_amdgcn_global_load_lds(
                (const __attribute__((address_space(1))) void*)(kg + row * 128 + scb),
                (__attribute__((address_space(3))) void*)((char*)Ks + i * 4096 + w * 1024),
                16, 0, 0);
            __builtin_amdgcn_global_load_lds(
                (const __attribute__((address_space(1))) void*)(vg + (size_t)row * (SS * 2) + scb),
                (__attribute__((address_space(3))) void*)((char*)Vs + i * 4096 + w * 1024),
                16, 0, 0);
        }
        int km[4];
        if (maskE) {
            #pragma unroll
            for (int n = 0; n < 4; ++n)
                km[n] = maskE[(size_t)b * SS + kt * KT + n * 16 + lr];
        }
        __syncthreads();

        // ---- QK^T: wave's 16 q rows x 64 keys ----
        f32x4 sacc[4];
        #pragma unroll
        for (int n = 0; n < 4; ++n) sacc[n] = (f32x4){0.f, 0.f, 0.f, 0.f};
        #pragma unroll
        for (int ks = 0; ks < 2; ++ks) {
            int qrow = qrow_base + lr;
            s16x8 aq = *(const s16x8*)((const char*)Qs +
                        qrow * 128 + ((ks * 64 + g * 16) ^ ((qrow & 7) << 4)));
            #pragma unroll
            for (int n = 0; n < 4; ++n) {
                int krow = n * 16 + lr;
                s16x8 bk = *(const s16x8*)((const char*)Ks +
                            krow * 128 + ((ks * 64 + g * 16) ^ ((krow & 7) << 4)));
                sacc[n] = __builtin_amdgcn_mfma_f32_16x16x32_bf16(aq, bk, sacc[n], 0, 0, 0);
            }
        }

        // ---- scale + mask ----
        #pragma unroll
        for (int n = 0; n < 4; ++n) {
            #pragma unroll
            for (int j = 0; j < 4; ++j) {
                float v = sacc[n][j] * 0.125f;
                if (causal) {
                    if (kt == qt && (n * 16 + lr > qrow_base + 4 * g + j)) v = -3.0e38f;
                } else {
                    if (km[n] != 0) v = -1e4f;
                }
                sacc[n][j] = v;
            }
        }

        // ---- online softmax (rows: 4g+j within wave frag; cols across 16 lanes) ----
        float mx[4];
        #pragma unroll
        for (int j = 0; j < 4; ++j)
            mx[j] = fmaxf(fmaxf(sacc[0][j], sacc[1][j]), fmaxf(sacc[2][j], sacc[3][j]));
        #pragma unroll
        for (int msk = 1; msk < 16; msk <<= 1) {
            #pragma unroll
            for (int j = 0; j < 4; ++j) mx[j] = fmaxf(mx[j], __shfl_xor(mx[j], msk));
        }
        float rs[4], psum[4];
        #pragma unroll
        for (int j = 0; j < 4; ++j) {
            float mn = fmaxf(mrun[j], mx[j]);
            rs[j] = expf(mrun[j] - mn);
            mrun[j] = mn;
            psum[j] = 0.f;
        }
        // p = exp(s - m), write to per-wave P region (wave-local, no barrier needed)
        #pragma unroll
        for (int n = 0; n < 4; ++n) {
            #pragma unroll
            for (int j = 0; j < 4; ++j) {
                float p = expf(sacc[n][j] - mrun[j]);
                psum[j] += p;
                int prow = qrow_base + 4 * g + j;
                int key = n * 16 + lr;
                *(bf16*)((char*)Ps + prow * 128 + ((2 * key) ^ ((prow & 7) << 4))) =
                    __float2bfloat16(p);
            }
        }
        #pragma unroll
        for (int msk = 1; msk < 16; msk <<= 1) {
            #pragma unroll
            for (int j = 0; j < 4; ++j) psum[j] += __shfl_xor(psum[j], msk);
        }
        #pragma unroll
        for (int j = 0; j < 4; ++j) lrun[j] = lrun[j] * rs[j] + psum[j];
        #pragma unroll
        for (int n = 0; n < 4; ++n) {
            #pragma unroll
            for (int j = 0; j < 4; ++j) oacc[n][j] *= rs[j];
        }

        // ---- PV: O[16q][64d] += P[16q][64key] @ V^T ----
        #pragma unroll
        for (int ks = 0; ks < 2; ++ks) {
            int prow = qrow_base + lr;
            s16x8 ap = *(const s16x8*)((const char*)Ps +
                        prow * 128 + ((ks * 64 + g * 16) ^ ((prow & 7) << 4)));
            #pragma unroll
            for (int n = 0; n < 4; ++n) {
                int vrow = n * 16 + lr;
                s16x8 bv = *(const s16x8*)((const char*)Vs +
                            vrow * 128 + ((ks * 64 + g * 16) ^ ((vrow & 7) << 4)));
                oacc[n] = __builtin_amdgcn_mfma_f32_16x16x32_bf16(ap, bv, oacc[n], 0, 0, 0);
            }
        }
        __syncthreads();    // before next tile's staging overwrites Ks/Vs
    }

    // ---- finalize ----
    float inv[4];
    #pragma unroll
    for (int j = 0; j < 4; ++j) inv[j] = 1.0f / lrun[j];
    #pragma unroll
    for (int n = 0; n < 4; ++n) {
        #pragma unroll
        for (int j = 0; j < 4; ++j) {
            int q = qt * QT + qrow_base + 4 * g + j;
            int d = n * 16 + lr;
            Out[((size_t)b * SS + q) * EE + h * DD + d] =
                __float2bfloat16(oacc[n][j] * inv[j]);
        }
    }
}

// ---------------- gate: acc (+)= alpha*lm*a + (1-alpha)*vm*e ------------------------
__global__ void gate_kernel(const float* __restrict__ logits, const float* __restrict__ a,
                            const float* __restrict__ e, float* __restrict__ acc,
                            const int* __restrict__ tau, int init)
{
    float thr = (float)tau[0];
    for (size_t i = (size_t)blockIdx.x * blockDim.x + threadIdx.x; i < NE;
         i += (size_t)gridDim.x * blockDim.x) {
        float al = 1.0f / (1.0f + expf(-logits[i]));
        float lm = (al > thr) ? 1.0f : 0.0f;
        float vm = (al < 1.0f - thr) ? 1.0f : 0.0f;
        float v = al * lm * a[i] + (1.0f - al) * vm * e[i];
        acc[i] = init ? v : (acc[i] + v);
    }
}

// ---------------- aq = acc / sqrt(3) * maskq[row] -----------------------------------
__global__ void scale_mask_kernel(float* __restrict__ acc, const float* __restrict__ maskq)
{
    for (size_t i = (size_t)blockIdx.x * blockDim.x + threadIdx.x; i < NE;
         i += (size_t)gridDim.x * blockDim.x) {
        acc[i] = acc[i] * 0.57735026918962576f * maskq[i / EE];
    }
}

extern "C" void kernel_launch(void* const* d_in, const int* in_sizes, int n_in,
                              void* d_out, int out_size, void* d_ws, size_t ws_size,
                              hipStream_t stream)
{
    const float* x        = (const float*)d_in[0];
    const float* enc      = (const float*)d_in[1];
    const float* maskq    = (const float*)d_in[2];
    const int*   mask_enc = (const int*)d_in[4];
    const int*   tau      = (const int*)d_in[6];
    const float* Wq = (const float*)d_in[7];
    const float* Wk = (const float*)d_in[8];
    const float* Wv = (const float*)d_in[9];
    const float* Wo = (const float*)d_in[10];
    const float* bo = (const float*)d_in[11];
    const float* fcq_w = (const float*)d_in[12];
    const float* fcq_b = (const float*)d_in[13];
    const float* fck_w = (const float*)d_in[14];
    const float* fck_b = (const float*)d_in[15];
    const float* fcv_w = (const float*)d_in[16];
    const float* fcv_b = (const float*)d_in[17];
    const float* cproj_w = (const float*)d_in[18];
    const float* cproj_b = (const float*)d_in[19];
    const float* ln1_g = (const float*)d_in[20];
    const float* ln1_b = (const float*)d_in[21];
    const float* ln2_g = (const float*)d_in[22];
    const float* ln2_b = (const float*)d_in[23];
    const float* cfc_w = (const float*)d_in[24];
    const float* cfc_b = (const float*)d_in[25];
    const float* cproj2_w = (const float*)d_in[26];
    const float* cproj2_b = (const float*)d_in[27];
    const float* aw[3] = {(const float*)d_in[28], (const float*)d_in[30], (const float*)d_in[32]};
    const float* ab[3] = {(const float*)d_in[29], (const float*)d_in[31], (const float*)d_in[33]};

    float* out   = (float*)d_out;       // [NTOK, E]
    float* kpres = out + NE;            // present[0]: [B,H,S,D] f32
    float* vpres = out + 2 * NE;        // present[1]

    float* ws   = (float*)d_ws;
    float* a    = ws + 0 * NE;          // residual after self-attn, f32
    float* ebuf = ws + 1 * NE;          // cross-attn branch output, f32
    float* acc  = ws + 2 * NE;          // gated sum -> aq, f32
    bf16* lnb     = (bf16*)(ws + 3 * NE);           // LN outputs
    bf16* attoutb = lnb + NE;                       // attention out bf16 [N,E]
    bf16* qbhb    = (bf16*)(ws + 4 * NE);           // q bf16 [B,H,S,D]
    bf16* kbhb    = qbhb + NE;                      // k bf16 [B,H,S,D]
    bf16* vbhb    = (bf16*)(ws + 5 * NE);           // v bf16 [B,H,D,S]
    bf16* abf     = vbhb + NE;                      // [NTOK][1536] bf16 = a | e
    bf16* mlphb   = (bf16*)(ws + 7 * NE);           // [NTOK][3072] bf16
    bf16* wp      = (bf16*)(ws + 9 * NE);           // transposed bf16 weights
    bf16* WqT = wp;            wp += 768 * 768;
    bf16* WkT = wp;            wp += 768 * 768;
    bf16* WvT = wp;            wp += 768 * 768;
    bf16* WoT = wp;            wp += 768 * 768;
    bf16* fcqT = wp;           wp += 768 * 768;
    bf16* fckT = wp;           wp += 768 * 768;
    bf16* fcvT = wp;           wp += 768 * 768;
    bf16* cprojT = wp;         wp += 768 * 768;
    bf16* awT[3];
    awT[0] = wp;               wp += 1536 * 768;
    awT[1] = wp;               wp += 1536 * 768;
    awT[2] = wp;               wp += 1536 * 768;
    bf16* cfcT = wp;           wp += (size_t)768 * 3072;   // [3072][768]
    bf16* cproj2T = wp;        wp += (size_t)3072 * 768;   // [768][3072]
    float* alpha = out;        // transient gate-logit scratch (overwritten by final GEMM)

    dim3 blk(256);
    dim3 gE(NTOK / TM, EE / TN);        // 32 x 6
    dim3 gF(NTOK / TM, FF / TN);        // 32 x 24
    dim3 gAttn(SS / QT, BB * HH);       // 8 x 96
    dim3 gT88(768 / 32, 768 / 32);
    dim3 gTaw(768 / 32, 1536 / 32);
    dim3 gTcf(3072 / 32, 768 / 32);
    dim3 gTcp(768 / 32, 3072 / 32);

    // 0. weight transpose+cast to bf16 [N][K]
    tcast_kernel<<<gT88, blk, 0, stream>>>(Wq, WqT, 768, 768);
    tcast_kernel<<<gT88, blk, 0, stream>>>(Wk, WkT, 768, 768);
    tcast_kernel<<<gT88, blk, 0, stream>>>(Wv, WvT, 768, 768);
    tcast_kernel<<<gT88, blk, 0, stream>>>(Wo, WoT, 768, 768);
    tcast_kernel<<<gT88, blk, 0, stream>>>(fcq_w, fcqT, 768, 768);
    tcast_kernel<<<gT88, blk, 0, stream>>>(fck_w, fckT, 768, 768);
    tcast_kernel<<<gT88, blk, 0, stream>>>(fcv_w, fcvT, 768, 768);
    tcast_kernel<<<gT88, blk, 0, stream>>>(cproj_w, cprojT, 768, 768);
    tcast_kernel<<<gTaw, blk, 0, stream>>>(aw[0], awT[0], 1536, 768);
    tcast_kernel<<<gTaw, blk, 0, stream>>>(aw[1], awT[1], 1536, 768);
    tcast_kernel<<<gTaw, blk, 0, stream>>>(aw[2], awT[2], 1536, 768);
    tcast_kernel<<<gTcf, blk, 0, stream>>>(cfc_w, cfcT, 768, 3072);
    tcast_kernel<<<gTcp, blk, 0, stream>>>(cproj2_w, cproj2T, 3072, 768);

    // 1. xl = ln1(x)
    ln_kernel<<<NTOK, blk, 0, stream>>>(x, lnb, ln1_g, ln1_b, 0, (size_t)SS * EE);
    // 2. self q,k,v: q bf16 only; k,v f32 present (d_out) + bf16 for attention
    mgemm_kernel<<<gE, blk, 0, stream>>>(lnb, WqT, nullptr, nullptr, qbhb, 0, nullptr, nullptr, EE, EE, EE, FLAG_CBSD);
    mgemm_kernel<<<gE, blk, 0, stream>>>(lnb, WkT, nullptr, kpres, kbhb, 0, nullptr, nullptr, EE, EE, EE, FLAG_BHSD | FLAG_CBSD);
    mgemm_kernel<<<gE, blk, 0, stream>>>(lnb, WvT, nullptr, vpres, vbhb, 0, nullptr, nullptr, EE, EE, EE, FLAG_BHSD | FLAG_CBDS);
    // 3. causal self-attention (bf16 MFMA)
    fattn2_kernel<<<gAttn, blk, 0, stream>>>(qbhb, kbhb, vbhb, nullptr, attoutb, 1);
    // 4. a = attout@Wo + bo + x (f32), bf16 copy into abf[:, 0:768]
    mgemm_kernel<<<gE, blk, 0, stream>>>(attoutb, WoT, bo, a, abf, 1536, x, nullptr, EE, EE, EE, FLAG_RES);
    // 5. al = ln1(a)
    ln_kernel<<<NTOK, blk, 0, stream>>>(a, lnb, ln1_g, ln1_b, 0, (size_t)SS * EE);
    // 6. cross q (shared across the 3 encoders)
    mgemm_kernel<<<gE, blk, 0, stream>>>(lnb, fcqT, fcq_b, nullptr, qbhb, 0, nullptr, nullptr, EE, EE, EE, FLAG_CBSD);
    // 7. three cross-attention branches + gates
    for (int idx = 0; idx < 3; ++idx) {
        ln_kernel<<<NTOK, blk, 0, stream>>>(enc, lnb, ln1_g, ln1_b,
                                            (size_t)idx * SS * EE, (size_t)3 * SS * EE);
        mgemm_kernel<<<gE, blk, 0, stream>>>(lnb, fckT, fck_b, nullptr, kbhb, 0, nullptr, nullptr, EE, EE, EE, FLAG_CBSD);
        mgemm_kernel<<<gE, blk, 0, stream>>>(lnb, fcvT, fcv_b, nullptr, vbhb, 0, nullptr, nullptr, EE, EE, EE, FLAG_CBDS);
        fattn2_kernel<<<gAttn, blk, 0, stream>>>(qbhb, kbhb, vbhb, mask_enc, attoutb, 0);
        // e = attout@cproj + b (f32 for gate, bf16 into abf[:, 768:1536])
        mgemm_kernel<<<gE, blk, 0, stream>>>(attoutb, cprojT, cproj_b, ebuf, abf + 768, 1536, nullptr, nullptr, EE, EE, EE, 0);
        // gate logits: [a,e] @ aw + ab (K=1536)
        mgemm_kernel<<<gE, blk, 0, stream>>>(abf, awT[idx], ab[idx], alpha, nullptr, 0, nullptr, nullptr, EE, 1536, 1536, 0);
        gate_kernel<<<2048, blk, 0, stream>>>(alpha, a, ebuf, acc, tau, idx == 0 ? 1 : 0);
    }
    // 8. aq = acc / sqrt3 * maskq
    scale_mask_kernel<<<2048, blk, 0, stream>>>(acc, maskq);
    // 9. aqln = ln2(aq)
    ln_kernel<<<NTOK, blk, 0, stream>>>(acc, lnb, ln2_g, ln2_b, 0, (size_t)SS * EE);
    // 10. mlph = gelu(aqln @ cfc + cfc_b) bf16
    mgemm_kernel<<<gF, blk, 0, stream>>>(lnb, cfcT, cfc_b, nullptr, mlphb, FF, nullptr, nullptr, FF, EE, EE, FLAG_GELU);
    // 11. out = (aq + mlph @ cproj2 + cproj2_b) * maskq
    mgemm_kernel<<<gE, blk, 0, stream>>>(mlphb, cproj2T, cproj2_b, out, nullptr, 0, acc, maskq, EE, FF, FF, FLAG_FIN);
}

// Round 7
// 840.435 us; speedup vs baseline: 7.7748x; 1.1976x over previous
//
#include <hip/hip_runtime.h>
#include <hip/hip_bf16.h>
#include <math.h>

typedef __hip_bfloat16 bf16;
typedef __attribute__((ext_vector_type(8))) short s16x8;
typedef __attribute__((ext_vector_type(4))) float f32x4;

#define BB 8
#define SS 512
#define EE 768
#define HH 12
#define DD 64
#define FF 3072
#define NTOK (BB * SS)            // 4096
#define NE ((size_t)NTOK * EE)    // 3,145,728

#define TM 128
#define TN 128
#define TK 64

#define QT 64
#define KT 64

#define FLAG_RES  4    // + Rsrc[row,col]
#define FLAG_GELU 8
#define FLAG_FIN  16   // out = (Rsrc + v) * maskq[row]
#define FLAG_CBSD 32   // Cb store [B',H,S,D] bf16
#define FLAG_QKV  128  // self QKV fused epilogue (N=2304)
#define FLAG_KV   256  // cross K|V fused epilogue (N=1536)
#define FLAG_GSEG 512  // gate logits: per-row-seg weights, dual-source A

#define AS1 const __attribute__((address_space(1))) void*
#define AS3 __attribute__((address_space(3))) void*

__device__ __forceinline__ float gelu_new(float x) {
    return 0.5f * x * (1.0f + tanhf(0.7978845608028654f * (x + 0.044715f * x * x * x)));
}

// ---------------- weight transpose+cast: src f32 [R][C] -> dst bf16 [C][R] ----------
__global__ __launch_bounds__(256) void tcast_kernel(
    const float* __restrict__ src, bf16* __restrict__ dst, int R, int C)
{
    __shared__ float t[32][33];
    int c0 = blockIdx.x * 32, r0 = blockIdx.y * 32;
    int tid = threadIdx.x;
    int x = tid & 31, y = tid >> 5;
    #pragma unroll
    for (int i = 0; i < 4; ++i) {
        int r = y + i * 8;
        t[r][x] = src[(size_t)(r0 + r) * C + c0 + x];
    }
    __syncthreads();
    #pragma unroll
    for (int i = 0; i < 4; ++i) {
        int c = y + i * 8;
        dst[(size_t)(c0 + c) * R + r0 + x] = __float2bfloat16(t[x][c]);
    }
}

// ---------------- LayerNorm (f32 in -> bf16 out); encmode decodes [B,3,S,E] ---------
__global__ __launch_bounds__(256) void ln_kernel(
    const float* __restrict__ in, bf16* __restrict__ out,
    const float* __restrict__ g, const float* __restrict__ bta, int encmode)
{
    int row = blockIdx.x;
    const float* x;
    if (encmode) {
        int idx = row >> 12, b = (row >> 9) & 7, s = row & 511;
        x = in + (((size_t)b * 3 + idx) * SS + s) * EE;
    } else {
        x = in + (size_t)row * EE;
    }
    int tid = threadIdx.x;

    float v0 = x[tid], v1 = x[tid + 256], v2 = x[tid + 512];
    float s1 = v0 + v1 + v2;
    float s2 = v0 * v0 + v1 * v1 + v2 * v2;
    #pragma unroll
    for (int o = 32; o > 0; o >>= 1) {
        s1 += __shfl_down(s1, o);
        s2 += __shfl_down(s2, o);
    }
    __shared__ float r1[4], r2[4];
    if ((tid & 63) == 0) { r1[tid >> 6] = s1; r2[tid >> 6] = s2; }
    __syncthreads();
    float mean = (r1[0] + r1[1] + r1[2] + r1[3]) * (1.0f / 768.0f);
    float ssq  = (r2[0] + r2[1] + r2[2] + r2[3]) * (1.0f / 768.0f);
    float rstd = rsqrtf(ssq - mean * mean + 1e-5f);

    bf16* y = out + (size_t)row * EE;
    y[tid]       = __float2bfloat16((v0 - mean) * rstd * g[tid]       + bta[tid]);
    y[tid + 256] = __float2bfloat16((v1 - mean) * rstd * g[tid + 256] + bta[tid + 256]);
    y[tid + 512] = __float2bfloat16((v2 - mean) * rstd * g[tid + 512] + bta[tid + 512]);
}

// ---------------- bf16 MFMA GEMM with fused epilogues -------------------------------
__global__ __launch_bounds__(256) void mgemm_kernel(
    const bf16* __restrict__ A, const bf16* __restrict__ A2,
    const bf16* __restrict__ Wt, const float* __restrict__ bias,
    float* __restrict__ Cf, bf16* __restrict__ Cb, bf16* __restrict__ Cb2,
    int ldcb, const float* __restrict__ Rsrc, const float* __restrict__ maskq,
    int Nn, int K, int lda, int flags)
{
    __shared__ __align__(16) bf16 smem[TM * TK + TN * TK];   // 32 KB
    bf16* As = smem;
    bf16* Bs = smem + TM * TK;
    int tid = threadIdx.x;
    int w = tid >> 6, l = tid & 63;
    int row0 = blockIdx.x * TM, col0 = blockIdx.y * TN;
    int wr = (w >> 1) * 64, wc = (w & 1) * 64;
    int lr = l & 15, lg = l >> 4;

    bool f_res  = flags & FLAG_RES;
    bool f_gelu = flags & FLAG_GELU;
    bool f_fin  = flags & FLAG_FIN;
    bool f_cbsd = flags & FLAG_CBSD;
    bool f_qkv  = flags & FLAG_QKV;
    bool f_kv   = flags & FLAG_KV;
    bool f_gseg = flags & FLAG_GSEG;

    const bf16* Wb = Wt;
    const float* bb_ = bias;
    if (f_gseg) {
        int seg = row0 >> 12;
        Wb = Wt + (size_t)seg * 1536 * 768;
        bb_ = bias + seg * 768;
    }

    f32x4 acc[4][4];
    #pragma unroll
    for (int m = 0; m < 4; ++m)
        #pragma unroll
        for (int n = 0; n < 4; ++n) acc[m][n] = (f32x4){0.f, 0.f, 0.f, 0.f};

    for (int kb = 0; kb < K; kb += TK) {
        #pragma unroll
        for (int i = 0; i < 4; ++i) {
            int e = (i * 256 + tid) * 8;
            int r = e >> 6, c = e & 63;
            const bf16* asrc;
            if (f_gseg) {
                int kg = kb + c;
                if (kg < 768) asrc = A  + (size_t)((row0 + r) & 4095) * lda + kg;
                else          asrc = A2 + (size_t)(row0 + r) * lda + (kg - 768);
            } else {
                asrc = A + (size_t)(row0 + r) * lda + kb + c;
            }
            __builtin_amdgcn_global_load_lds((AS1)asrc,
                (AS3)((char*)As + i * 4096 + w * 1024), 16, 0, 0);
            __builtin_amdgcn_global_load_lds((AS1)(Wb + (size_t)(col0 + r) * K + kb + c),
                (AS3)((char*)Bs + i * 4096 + w * 1024), 16, 0, 0);
        }
        __syncthreads();
        #pragma unroll
        for (int ks = 0; ks < 2; ++ks) {
            s16x8 af[4], bfr[4];
            #pragma unroll
            for (int m = 0; m < 4; ++m)
                af[m] = *(const s16x8*)(As + (wr + m * 16 + lr) * TK + ks * 32 + lg * 8);
            #pragma unroll
            for (int n = 0; n < 4; ++n)
                bfr[n] = *(const s16x8*)(Bs + (wc + n * 16 + lr) * TK + ks * 32 + lg * 8);
            #pragma unroll
            for (int m = 0; m < 4; ++m)
                #pragma unroll
                for (int n = 0; n < 4; ++n)
                    acc[m][n] = __builtin_amdgcn_mfma_f32_16x16x32_bf16(
                        af[m], bfr[n], acc[m][n], 0, 0, 0);
        }
        __syncthreads();
    }

    int gh0 = (col0 + wc) >> 6;
    bool vquad = (f_qkv && gh0 >= 24) || (f_kv && gh0 >= 12);
    bf16* T = smem + w * 4096;   // per-wave 8KB transpose buffer (As/Bs dead)

    #pragma unroll
    for (int m = 0; m < 4; ++m) {
        #pragma unroll
        for (int n = 0; n < 4; ++n) {
            #pragma unroll
            for (int j = 0; j < 4; ++j) {
                int row = row0 + wr + m * 16 + lg * 4 + j;
                int col = col0 + wc + n * 16 + lr;
                size_t lin = (size_t)row * Nn + col;
                float v = acc[m][n][j];
                if (bb_)    v += bb_[col];
                if (f_res)  v += Rsrc[lin];
                if (f_gelu) v = gelu_new(v);
                if (f_fin)  v = (Rsrc[lin] + v) * maskq[row];
                int bb = row >> 9, s = row & 511;
                int gh = col >> 6, d = col & 63;
                if (f_qkv) {
                    if (gh < 12) {
                        Cb[(((size_t)bb * HH + gh) * SS + s) * DD + d] = __float2bfloat16(v);
                    } else if (gh < 24) {
                        Cf[(((size_t)bb * HH + (gh - 12)) * SS + s) * DD + d] = v;
                        Cb[NE + (((size_t)bb * HH + (gh - 12)) * SS + s) * DD + d] = __float2bfloat16(v);
                    } else {
                        Cf[NE + (((size_t)bb * HH + (gh - 24)) * SS + s) * DD + d] = v;
                        int rl = m * 16 + lg * 4 + j, cl = n * 16 + lr;
                        *(bf16*)((char*)T + cl * 128 + ((rl * 2) ^ ((cl & 7) << 4))) =
                            __float2bfloat16(v);
                    }
                } else if (f_kv) {
                    if (gh < 12) {
                        Cb[(((size_t)bb * HH + gh) * SS + s) * DD + d] = __float2bfloat16(v);
                    } else {
                        int rl = m * 16 + lg * 4 + j, cl = n * 16 + lr;
                        *(bf16*)((char*)T + cl * 128 + ((rl * 2) ^ ((cl & 7) << 4))) =
                            __float2bfloat16(v);
                    }
                } else if (f_cbsd) {
                    Cb[(((size_t)bb * HH + gh) * SS + s) * DD + d] = __float2bfloat16(v);
                } else {
                    if (Cf) Cf[lin] = v;
                    if (Cb) Cb[(size_t)row * ldcb + col] = __float2bfloat16(v);
                }
            }
        }
    }

    if (vquad) {   // wave-uniform; coalesced store of V^T [B',H,D,S]
        int b2 = (row0 + wr) >> 9;
        int s0 = (row0 + wr) & 511;
        int hV = gh0 - (f_qkv ? 24 : 12);
        bf16* vb = Cb2 + (((size_t)b2 * HH + hV) * DD) * SS + s0;
        #pragma unroll
        for (int p = 0; p < 8; ++p) {
            int dl = p * 8 + (l >> 3);
            int ch = l & 7;
            int cs = ch ^ (dl & 7);
            s16x8 vv = *(const s16x8*)((char*)T + dl * 128 + cs * 16);
            *(s16x8*)(vb + (size_t)dl * SS + ch * 8) = vv;
        }
    }
}

// ---------------- bf16 MFMA flash attention (batched over b') -----------------------
__global__ __launch_bounds__(256) void fattn2_kernel(
    const bf16* __restrict__ Qb, const bf16* __restrict__ Kb,
    const bf16* __restrict__ Vb, const int* __restrict__ maskE,
    bf16* __restrict__ Out, int causal)
{
    int qt = blockIdx.x, bh = blockIdx.y;
    int bp = bh / HH, h = bh % HH;     // b' (0..23 cross, 0..7 self)
    int bq = bp & 7;                   // underlying batch for Q / mask
    int tid = threadIdx.x;
    int w = tid >> 6, l = tid & 63;
    int lr = l & 15, g = l >> 4;

    __shared__ __align__(16) bf16 Qs[64 * 64];
    __shared__ __align__(16) bf16 Ks[64 * 64];
    __shared__ __align__(16) bf16 Vs[64 * 64];
    __shared__ __align__(16) bf16 Ps[64 * 64];

    int p0 = w * 1024 + l * 16;
    {
        const char* qg = (const char*)(Qb + (((size_t)bq * HH + h) * SS + qt * QT) * DD);
        #pragma unroll
        for (int i = 0; i < 2; ++i) {
            int p = i * 4096 + p0;
            int row = p >> 7, cb = p & 127;
            int scb = cb ^ ((row & 7) << 4);
            __builtin_amdgcn_global_load_lds((AS1)(qg + row * 128 + scb),
                (AS3)((char*)Qs + i * 4096 + w * 1024), 16, 0, 0);
        }
    }

    float mrun[4], lrun[4];
    f32x4 oacc[4];
    #pragma unroll
    for (int j = 0; j < 4; ++j) { mrun[j] = -3.0e38f; lrun[j] = 0.f; }
    #pragma unroll
    for (int n = 0; n < 4; ++n) oacc[n] = (f32x4){0.f, 0.f, 0.f, 0.f};

    int ntiles = causal ? (qt + 1) : (SS / KT);
    int qrow_base = w * 16;

    for (int kt = 0; kt < ntiles; ++kt) {
        const char* kg = (const char*)(Kb + ((size_t)bh * SS + kt * KT) * DD);
        const char* vg = (const char*)(Vb + (size_t)bh * DD * SS + (size_t)kt * KT);
        #pragma unroll
        for (int i = 0; i < 2; ++i) {
            int p = i * 4096 + p0;
            int row = p >> 7, cb = p & 127;
            int scb = cb ^ ((row & 7) << 4);
            __builtin_amdgcn_global_load_lds((AS1)(kg + row * 128 + scb),
                (AS3)((char*)Ks + i * 4096 + w * 1024), 16, 0, 0);
            __builtin_amdgcn_global_load_lds((AS1)(vg + (size_t)row * (SS * 2) + scb),
                (AS3)((char*)Vs + i * 4096 + w * 1024), 16, 0, 0);
        }
        int km[4];
        if (maskE) {
            #pragma unroll
            for (int n = 0; n < 4; ++n)
                km[n] = maskE[(size_t)bq * SS + kt * KT + n * 16 + lr];
        }
        __syncthreads();

        f32x4 sacc[4];
        #pragma unroll
        for (int n = 0; n < 4; ++n) sacc[n] = (f32x4){0.f, 0.f, 0.f, 0.f};
        #pragma unroll
        for (int ks = 0; ks < 2; ++ks) {
            int qrow = qrow_base + lr;
            s16x8 aq = *(const s16x8*)((const char*)Qs +
                        qrow * 128 + ((ks * 64 + g * 16) ^ ((qrow & 7) << 4)));
            #pragma unroll
            for (int n = 0; n < 4; ++n) {
                int krow = n * 16 + lr;
                s16x8 bk = *(const s16x8*)((const char*)Ks +
                            krow * 128 + ((ks * 64 + g * 16) ^ ((krow & 7) << 4)));
                sacc[n] = __builtin_amdgcn_mfma_f32_16x16x32_bf16(aq, bk, sacc[n], 0, 0, 0);
            }
        }

        #pragma unroll
        for (int n = 0; n < 4; ++n) {
            #pragma unroll
            for (int j = 0; j < 4; ++j) {
                float v = sacc[n][j] * 0.125f;
                if (causal) {
                    if (kt == qt && (n * 16 + lr > qrow_base + 4 * g + j)) v = -3.0e38f;
                } else {
                    if (km[n] != 0) v = -1e4f;
                }
                sacc[n][j] = v;
            }
        }

        float mx[4];
        #pragma unroll
        for (int j = 0; j < 4; ++j)
            mx[j] = fmaxf(fmaxf(sacc[0][j], sacc[1][j]), fmaxf(sacc[2][j], sacc[3][j]));
        #pragma unroll
        for (int msk = 1; msk < 16; msk <<= 1) {
            #pragma unroll
            for (int j = 0; j < 4; ++j) mx[j] = fmaxf(mx[j], __shfl_xor(mx[j], msk));
        }
        float rs[4], psum[4];
        #pragma unroll
        for (int j = 0; j < 4; ++j) {
            float mn = fmaxf(mrun[j], mx[j]);
            rs[j] = expf(mrun[j] - mn);
            mrun[j] = mn;
            psum[j] = 0.f;
        }
        #pragma unroll
        for (int n = 0; n < 4; ++n) {
            #pragma unroll
            for (int j = 0; j < 4; ++j) {
                float p = expf(sacc[n][j] - mrun[j]);
                psum[j] += p;
                int prow = qrow_base + 4 * g + j;
                int key = n * 16 + lr;
                *(bf16*)((char*)Ps + prow * 128 + ((2 * key) ^ ((prow & 7) << 4))) =
                    __float2bfloat16(p);
            }
        }
        #pragma unroll
        for (int msk = 1; msk < 16; msk <<= 1) {
            #pragma unroll
            for (int j = 0; j < 4; ++j) psum[j] += __shfl_xor(psum[j], msk);
        }
        #pragma unroll
        for (int j = 0; j < 4; ++j) lrun[j] = lrun[j] * rs[j] + psum[j];
        #pragma unroll
        for (int n = 0; n < 4; ++n) {
            #pragma unroll
            for (int j = 0; j < 4; ++j) oacc[n][j] *= rs[j];
        }

        #pragma unroll
        for (int ks = 0; ks < 2; ++ks) {
            int prow = qrow_base + lr;
            s16x8 ap = *(const s16x8*)((const char*)Ps +
                        prow * 128 + ((ks * 64 + g * 16) ^ ((prow & 7) << 4)));
            #pragma unroll
            for (int n = 0; n < 4; ++n) {
                int vrow = n * 16 + lr;
                s16x8 bv = *(const s16x8*)((const char*)Vs +
                            vrow * 128 + ((ks * 64 + g * 16) ^ ((vrow & 7) << 4)));
                oacc[n] = __builtin_amdgcn_mfma_f32_16x16x32_bf16(ap, bv, oacc[n], 0, 0, 0);
            }
        }
        __syncthreads();
    }

    float inv[4];
    #pragma unroll
    for (int j = 0; j < 4; ++j) inv[j] = 1.0f / lrun[j];
    #pragma unroll
    for (int n = 0; n < 4; ++n) {
        #pragma unroll
        for (int j = 0; j < 4; ++j) {
            int q = qt * QT + qrow_base + 4 * g + j;
            int d = n * 16 + lr;
            Out[((size_t)bp * SS + q) * EE + h * DD + d] =
                __float2bfloat16(oacc[n][j] * inv[j]);
        }
    }
}

// ---------------- fused 3-branch gate + /sqrt3 + maskq ------------------------------
__global__ void gate3_kernel(const float* __restrict__ logits, const float* __restrict__ a,
                             const bf16* __restrict__ e, float* __restrict__ acc,
                             const int* __restrict__ tau, const float* __restrict__ maskq)
{
    float thr = (float)tau[0];
    for (size_t i = (size_t)blockIdx.x * blockDim.x + threadIdx.x; i < NE;
         i += (size_t)gridDim.x * blockDim.x) {
        float av = a[i];
        float r = 0.f;
        #pragma unroll
        for (int idx = 0; idx < 3; ++idx) {
            float lg = logits[(size_t)idx * NE + i];
            float ev = __bfloat162float(e[(size_t)idx * NE + i]);
            float al = 1.0f / (1.0f + expf(-lg));
            float lm = (al > thr) ? 1.0f : 0.0f;
            float vm = (al < 1.0f - thr) ? 1.0f : 0.0f;
            r += al * lm * av + (1.0f - al) * vm * ev;
        }
        acc[i] = r * 0.57735026918962576f * maskq[i / EE];
    }
}

extern "C" void kernel_launch(void* const* d_in, const int* in_sizes, int n_in,
                              void* d_out, int out_size, void* d_ws, size_t ws_size,
                              hipStream_t stream)
{
    const float* x        = (const float*)d_in[0];
    const float* enc      = (const float*)d_in[1];
    const float* maskq    = (const float*)d_in[2];
    const int*   mask_enc = (const int*)d_in[4];
    const int*   tau      = (const int*)d_in[6];
    const float* Wq = (const float*)d_in[7];
    const float* Wk = (const float*)d_in[8];
    const float* Wv = (const float*)d_in[9];
    const float* Wo = (const float*)d_in[10];
    const float* bo = (const float*)d_in[11];
    const float* fcq_w = (const float*)d_in[12];
    const float* fcq_b = (const float*)d_in[13];
    const float* fck_w = (const float*)d_in[14];
    const float* fck_b = (const float*)d_in[15];
    const float* fcv_w = (const float*)d_in[16];
    const float* fcv_b = (const float*)d_in[17];
    const float* cproj_w = (const float*)d_in[18];
    const float* cproj_b = (const float*)d_in[19];
    const float* ln1_g = (const float*)d_in[20];
    const float* ln1_b = (const float*)d_in[21];
    const float* ln2_g = (const float*)d_in[22];
    const float* ln2_b = (const float*)d_in[23];
    const float* cfc_w = (const float*)d_in[24];
    const float* cfc_b = (const float*)d_in[25];
    const float* cproj2_w = (const float*)d_in[26];
    const float* cproj2_b = (const float*)d_in[27];
    const float* aw[3] = {(const float*)d_in[28], (const float*)d_in[30], (const float*)d_in[32]};
    const float* ab[3] = {(const float*)d_in[29], (const float*)d_in[31], (const float*)d_in[33]};

    float* out   = (float*)d_out;       // [NTOK, E]
    float* kpres = out + NE;            // present K [B,H,S,D] f32 (V at +NE)

    float* ws  = (float*)d_ws;
    float* a     = ws;                  // NE f32
    float* acc   = ws + NE;             // NE f32
    float* R     = ws + 2 * NE;         // 3*NE f32, time-shared:
    bf16*  kb_c   = (bf16*)R;           //   cross K [24,H,S,D] (3 NE-bf16)
    bf16*  vb_c   = kb_c + 3 * NE;      //   cross V^T [24,H,D,S] (3 NE-bf16)
    float* logits = R;                  //   gate logits [3][NE] f32
    bf16*  mlphb  = (bf16*)R;           //   MLP hidden bf16 [NTOK][FF]

    bf16* bbase = (bf16*)(ws + 5 * NE);
    bf16* lnb   = bbase;                // u0: ln out / self-attn out (sequenced)
    bf16* atts  = bbase;                //     alias of u0
    bf16* lnenc = bbase + NE;           // u1-3: ln(enc) -> cross-attn out
    bf16* attc  = lnenc;
    bf16* a_bf  = bbase + 4 * NE;       // u4
    bf16* e_bf  = bbase + 5 * NE;       // u5-7
    bf16* qbhb  = bbase + 8 * NE;       // u8
    bf16* kbhb  = bbase + 9 * NE;       // u9 (self K)
    bf16* vbhb  = bbase + 10 * NE;      // u10 (self V^T)
    bf16* wp    = bbase + 11 * NE;      // weights
    bf16* WqkvT = wp;          wp += 3 * 768 * 768;    // [2304][768] (q|k|v)
    bf16* WoT = wp;            wp += 768 * 768;
    bf16* fcqT = wp;           wp += 768 * 768;
    bf16* fckvT = wp;          wp += 2 * 768 * 768;    // [1536][768] (k|v)
    bf16* cprojT = wp;         wp += 768 * 768;
    bf16* awT = wp;            wp += (size_t)3 * 1536 * 768;
    bf16* cfcT = wp;           wp += (size_t)768 * 3072;   // [3072][768]
    bf16* cproj2T = wp;        wp += (size_t)3072 * 768;   // [768][3072]
    float* kvb = (float*)wp;            // [1536] = fck_b|fcv_b
    float* gb  = kvb + 1536;            // [2304] = ab0|ab1|ab2

    dim3 blk(256);
    dim3 gT88(24, 24), gTaw(24, 48), gTcf(96, 24), gTcp(24, 96);

    // 0. weights -> bf16 [N][K]; concat biases (d2d async, graph-safe)
    tcast_kernel<<<gT88, blk, 0, stream>>>(Wq, WqkvT, 768, 768);
    tcast_kernel<<<gT88, blk, 0, stream>>>(Wk, WqkvT + 768 * 768, 768, 768);
    tcast_kernel<<<gT88, blk, 0, stream>>>(Wv, WqkvT + 2 * 768 * 768, 768, 768);
    tcast_kernel<<<gT88, blk, 0, stream>>>(Wo, WoT, 768, 768);
    tcast_kernel<<<gT88, blk, 0, stream>>>(fcq_w, fcqT, 768, 768);
    tcast_kernel<<<gT88, blk, 0, stream>>>(fck_w, fckvT, 768, 768);
    tcast_kernel<<<gT88, blk, 0, stream>>>(fcv_w, fckvT + 768 * 768, 768, 768);
    tcast_kernel<<<gT88, blk, 0, stream>>>(cproj_w, cprojT, 768, 768);
    tcast_kernel<<<gTaw, blk, 0, stream>>>(aw[0], awT, 1536, 768);
    tcast_kernel<<<gTaw, blk, 0, stream>>>(aw[1], awT + 1536 * 768, 1536, 768);
    tcast_kernel<<<gTaw, blk, 0, stream>>>(aw[2], awT + 2 * 1536 * 768, 1536, 768);
    tcast_kernel<<<gTcf, blk, 0, stream>>>(cfc_w, cfcT, 768, 3072);
    tcast_kernel<<<gTcp, blk, 0, stream>>>(cproj2_w, cproj2T, 3072, 768);
    hipMemcpyAsync(kvb, fck_b, 768 * 4, hipMemcpyDeviceToDevice, stream);
    hipMemcpyAsync(kvb + 768, fcv_b, 768 * 4, hipMemcpyDeviceToDevice, stream);
    hipMemcpyAsync(gb, ab[0], 768 * 4, hipMemcpyDeviceToDevice, stream);
    hipMemcpyAsync(gb + 768, ab[1], 768 * 4, hipMemcpyDeviceToDevice, stream);
    hipMemcpyAsync(gb + 1536, ab[2], 768 * 4, hipMemcpyDeviceToDevice, stream);

    // 1. xl = ln1(x)
    ln_kernel<<<NTOK, blk, 0, stream>>>(x, lnb, ln1_g, ln1_b, 0);
    // 2. fused self QKV (N=2304): q->qbhb, k->kpres+kbhb, v->vpres+vbhb(V^T)
    mgemm_kernel<<<dim3(32, 18), blk, 0, stream>>>(lnb, nullptr, WqkvT, nullptr,
        kpres, qbhb, vbhb, 0, nullptr, nullptr, 2304, 768, 768, FLAG_QKV);
    // 3. causal self-attention
    fattn2_kernel<<<dim3(8, 96), blk, 0, stream>>>(qbhb, kbhb, vbhb, nullptr, atts, 1);
    // 4. a = attout@Wo + bo + x ; bf16 copy a_bf
    mgemm_kernel<<<dim3(32, 6), blk, 0, stream>>>(atts, nullptr, WoT, bo,
        a, a_bf, nullptr, 768, x, nullptr, 768, 768, 768, FLAG_RES);
    // 5. al = ln1(a)
    ln_kernel<<<NTOK, blk, 0, stream>>>(a, lnb, ln1_g, ln1_b, 0);
    // 6. cross q
    mgemm_kernel<<<dim3(32, 6), blk, 0, stream>>>(lnb, nullptr, fcqT, fcq_b,
        nullptr, qbhb, nullptr, 0, nullptr, nullptr, 768, 768, 768, FLAG_CBSD);
    // 7. batched 3-encoder pipeline
    ln_kernel<<<3 * NTOK, blk, 0, stream>>>(enc, lnenc, ln1_g, ln1_b, 1);
    mgemm_kernel<<<dim3(96, 12), blk, 0, stream>>>(lnenc, nullptr, fckvT, kvb,
        nullptr, kb_c, vb_c, 0, nullptr, nullptr, 1536, 768, 768, FLAG_KV);
    fattn2_kernel<<<dim3(8, 288), blk, 0, stream>>>(qbhb, kb_c, vb_c, mask_enc, attc, 0);
    mgemm_kernel<<<dim3(96, 6), blk, 0, stream>>>(attc, nullptr, cprojT, cproj_b,
        nullptr, e_bf, nullptr, 768, nullptr, nullptr, 768, 768, 768, 0);
    mgemm_kernel<<<dim3(96, 6), blk, 0, stream>>>(a_bf, e_bf, awT, gb,
        logits, nullptr, nullptr, 0, nullptr, nullptr, 768, 1536, 768, FLAG_GSEG);
    gate3_kernel<<<2048, blk, 0, stream>>>(logits, a, e_bf, acc, tau, maskq);
    // 8. aqln = ln2(aq)
    ln_kernel<<<NTOK, blk, 0, stream>>>(acc, lnb, ln2_g, ln2_b, 0);
    // 9. MLP
    mgemm_kernel<<<dim3(32, 24), blk, 0, stream>>>(lnb, nullptr, cfcT, cfc_b,
        nullptr, mlphb, nullptr, 3072, nullptr, nullptr, 3072, 768, 768, FLAG_GELU);
    mgemm_kernel<<<dim3(32, 6), blk, 0, stream>>>(mlphb, nullptr, cproj2T, cproj2_b,
        out, nullptr, nullptr, 0, acc, maskq, 768, 3072, 3072, FLAG_FIN);
}

// Round 10
// 711.531 us; speedup vs baseline: 9.1833x; 1.1812x over previous
//
#include <hip/hip_runtime.h>
#include <hip/hip_bf16.h>
#include <math.h>

typedef __hip_bfloat16 bf16;
typedef __attribute__((ext_vector_type(8))) short s16x8;
typedef __attribute__((ext_vector_type(4))) float f32x4;

#define BB 8
#define SS 512
#define EE 768
#define HH 12
#define DD 64
#define FF 3072
#define NTOK (BB * SS)            // 4096
#define NE ((size_t)NTOK * EE)    // 3,145,728

#define TM 128
#define TN 128
#define TK 64

#define QT 64
#define KT 64

#define FLAG_RES  4    // + Rsrc[row,col]
#define FLAG_GELU 8
#define FLAG_FIN  16   // out = (Rsrc + v) * maskq[row]
#define FLAG_CBSD 32   // Cb store [B',H,S,D] bf16
#define FLAG_QKV  128  // self QKV fused epilogue (N=2304)
#define FLAG_KV   256  // cross K|V fused epilogue (N=1536)
#define FLAG_GSEG 512  // gate logits: per-row-seg weights, dual-source A

#define AS1 const __attribute__((address_space(1))) void*
#define AS3 __attribute__((address_space(3))) void*

__device__ __forceinline__ float gelu_new(float x) {
    // 0.5x(1+tanh(u)) == x * sigmoid(2u), u = 0.79788456(x + 0.044715 x^3)
    float u2 = 1.5957691216057308f * (x + 0.044715f * x * x * x);
    return x / (1.0f + __expf(-u2));
}

// ---------------- weight transpose+cast: src f32 [R][C] -> dst bf16 [C][R] ----------
__global__ __launch_bounds__(256) void tcast_kernel(
    const float* __restrict__ src, bf16* __restrict__ dst, int R, int C)
{
    __shared__ float t[32][33];
    int c0 = blockIdx.x * 32, r0 = blockIdx.y * 32;
    int tid = threadIdx.x;
    int x = tid & 31, y = tid >> 5;
    #pragma unroll
    for (int i = 0; i < 4; ++i) {
        int r = y + i * 8;
        t[r][x] = src[(size_t)(r0 + r) * C + c0 + x];
    }
    __syncthreads();
    #pragma unroll
    for (int i = 0; i < 4; ++i) {
        int c = y + i * 8;
        dst[(size_t)(c0 + c) * R + r0 + x] = __float2bfloat16(t[x][c]);
    }
}

// ---------------- LayerNorm (f32 in -> bf16 out); encmode decodes [B,3,S,E] ---------
__global__ __launch_bounds__(256) void ln_kernel(
    const float* __restrict__ in, bf16* __restrict__ out,
    const float* __restrict__ g, const float* __restrict__ bta, int encmode)
{
    int row = blockIdx.x;
    const float* x;
    if (encmode) {
        int idx = row >> 12, b = (row >> 9) & 7, s = row & 511;
        x = in + (((size_t)b * 3 + idx) * SS + s) * EE;
    } else {
        x = in + (size_t)row * EE;
    }
    int tid = threadIdx.x;

    float v0 = x[tid], v1 = x[tid + 256], v2 = x[tid + 512];
    float s1 = v0 + v1 + v2;
    float s2 = v0 * v0 + v1 * v1 + v2 * v2;
    #pragma unroll
    for (int o = 32; o > 0; o >>= 1) {
        s1 += __shfl_down(s1, o);
        s2 += __shfl_down(s2, o);
    }
    __shared__ float r1[4], r2[4];
    if ((tid & 63) == 0) { r1[tid >> 6] = s1; r2[tid >> 6] = s2; }
    __syncthreads();
    float mean = (r1[0] + r1[1] + r1[2] + r1[3]) * (1.0f / 768.0f);
    float ssq  = (r2[0] + r2[1] + r2[2] + r2[3]) * (1.0f / 768.0f);
    float rstd = rsqrtf(ssq - mean * mean + 1e-5f);

    bf16* y = out + (size_t)row * EE;
    y[tid]       = __float2bfloat16((v0 - mean) * rstd * g[tid]       + bta[tid]);
    y[tid + 256] = __float2bfloat16((v1 - mean) * rstd * g[tid + 256] + bta[tid + 256]);
    y[tid + 512] = __float2bfloat16((v2 - mean) * rstd * g[tid + 512] + bta[tid + 512]);
}

// ---------------- bf16 MFMA GEMM: double-buffered prefetch + XCD swizzle ------------
__global__ __launch_bounds__(256) void mgemm_kernel(
    const bf16* __restrict__ A, const bf16* __restrict__ A2,
    const bf16* __restrict__ Wt, const float* __restrict__ bias,
    float* __restrict__ Cf, bf16* __restrict__ Cb, bf16* __restrict__ Cb2,
    int ldcb, const float* __restrict__ Rsrc, const float* __restrict__ maskq,
    int Nn, int K, int lda, int flags)
{
    __shared__ __align__(16) bf16 smem[2 * (TM * TK + TN * TK)];   // 64 KB
    const int BUFE = TM * TK + TN * TK;                            // elements per buffer
    int tid = threadIdx.x;
    int w = tid >> 6, l = tid & 63;

    // XCD-aware bijective swizzle (all grids have nwg % 8 == 0); row-band decode
    int gx = gridDim.x, gy = gridDim.y;
    int orig = blockIdx.y * gx + blockIdx.x;
    int cpx = (gx * gy) >> 3;
    int swz = (orig & 7) * cpx + (orig >> 3);
    int bx = swz / gy, by = swz % gy;
    int row0 = bx * TM, col0 = by * TN;

    int wr = (w >> 1) * 64, wc = (w & 1) * 64;
    int lr = l & 15, lg = l >> 4;

    bool f_res  = flags & FLAG_RES;
    bool f_gelu = flags & FLAG_GELU;
    bool f_fin  = flags & FLAG_FIN;
    bool f_cbsd = flags & FLAG_CBSD;
    bool f_qkv  = flags & FLAG_QKV;
    bool f_kv   = flags & FLAG_KV;
    bool f_gseg = flags & FLAG_GSEG;

    const bf16* Wb = Wt;
    const float* bb_ = bias;
    if (f_gseg) {
        int seg = row0 >> 12;
        Wb = Wt + (size_t)seg * 1536 * 768;
        bb_ = bias + seg * 768;
    }

    f32x4 acc[4][4];
    #pragma unroll
    for (int m = 0; m < 4; ++m)
        #pragma unroll
        for (int n = 0; n < 4; ++n) acc[m][n] = (f32x4){0.f, 0.f, 0.f, 0.f};

    auto stage = [&](int buf, int kb) {
        bf16* As_ = smem + buf * BUFE;
        bf16* Bs_ = As_ + TM * TK;
        #pragma unroll
        for (int i = 0; i < 4; ++i) {
            int e = (i * 256 + tid) * 8;
            int r = e >> 6, c = e & 63;
            const bf16* asrc;
            if (f_gseg) {
                int kg = kb + c;
                if (kg < 768) asrc = A  + (size_t)((row0 + r) & 4095) * lda + kg;
                else          asrc = A2 + (size_t)(row0 + r) * lda + (kg - 768);
            } else {
                asrc = A + (size_t)(row0 + r) * lda + kb + c;
            }
            __builtin_amdgcn_global_load_lds((AS1)asrc,
                (AS3)((char*)As_ + i * 4096 + w * 1024), 16, 0, 0);
            __builtin_amdgcn_global_load_lds((AS1)(Wb + (size_t)(col0 + r) * K + kb + c),
                (AS3)((char*)Bs_ + i * 4096 + w * 1024), 16, 0, 0);
        }
    };

    int nk = K / TK;
    stage(0, 0);
    __syncthreads();                       // drains prologue loads
    for (int t = 0; t < nk; ++t) {
        int cur = t & 1;
        if (t + 1 < nk) stage(cur ^ 1, (t + 1) * TK);   // prefetch next tile (in flight)
        const bf16* As = smem + cur * BUFE;
        const bf16* Bs = As + TM * TK;
        #pragma unroll
        for (int ks = 0; ks < 2; ++ks) {
            s16x8 af[4], bfr[4];
            #pragma unroll
            for (int m = 0; m < 4; ++m)
                af[m] = *(const s16x8*)(As + (wr + m * 16 + lr) * TK + ks * 32 + lg * 8);
            #pragma unroll
            for (int n = 0; n < 4; ++n)
                bfr[n] = *(const s16x8*)(Bs + (wc + n * 16 + lr) * TK + ks * 32 + lg * 8);
            #pragma unroll
            for (int m = 0; m < 4; ++m)
                #pragma unroll
                for (int n = 0; n < 4; ++n)
                    acc[m][n] = __builtin_amdgcn_mfma_f32_16x16x32_bf16(
                        af[m], bfr[n], acc[m][n], 0, 0, 0);
        }
        __syncthreads();                   // drain prefetch + protect buffer reuse
    }

    int gh0 = (col0 + wc) >> 6;
    bool vquad = (f_qkv && gh0 >= 24) || (f_kv && gh0 >= 12);
    bf16* T = smem + w * 4096;   // per-wave 8KB transpose buffer (smem dead post-loop)

    #pragma unroll
    for (int m = 0; m < 4; ++m) {
        #pragma unroll
        for (int n = 0; n < 4; ++n) {
            #pragma unroll
            for (int j = 0; j < 4; ++j) {
                int row = row0 + wr + m * 16 + lg * 4 + j;
                int col = col0 + wc + n * 16 + lr;
                size_t lin = (size_t)row * Nn + col;
                float v = acc[m][n][j];
                if (bb_)    v += bb_[col];
                if (f_res)  v += Rsrc[lin];
                if (f_gelu) v = gelu_new(v);
                if (f_fin)  v = (Rsrc[lin] + v) * maskq[row];
                int bb = row >> 9, s = row & 511;
                int gh = col >> 6, d = col & 63;
                if (f_qkv) {
                    if (gh < 12) {
                        Cb[(((size_t)bb * HH + gh) * SS + s) * DD + d] = __float2bfloat16(v);
                    } else if (gh < 24) {
                        Cf[(((size_t)bb * HH + (gh - 12)) * SS + s) * DD + d] = v;
                        Cb[NE + (((size_t)bb * HH + (gh - 12)) * SS + s) * DD + d] = __float2bfloat16(v);
                    } else {
                        Cf[NE + (((size_t)bb * HH + (gh - 24)) * SS + s) * DD + d] = v;
                        int rl = m * 16 + lg * 4 + j, cl = n * 16 + lr;
                        *(bf16*)((char*)T + cl * 128 + ((rl * 2) ^ ((cl & 7) << 4))) =
                            __float2bfloat16(v);
                    }
                } else if (f_kv) {
                    if (gh < 12) {
                        Cb[(((size_t)bb * HH + gh) * SS + s) * DD + d] = __float2bfloat16(v);
                    } else {
                        int rl = m * 16 + lg * 4 + j, cl = n * 16 + lr;
                        *(bf16*)((char*)T + cl * 128 + ((rl * 2) ^ ((cl & 7) << 4))) =
                            __float2bfloat16(v);
                    }
                } else if (f_cbsd) {
                    Cb[(((size_t)bb * HH + gh) * SS + s) * DD + d] = __float2bfloat16(v);
                } else {
                    if (Cf) Cf[lin] = v;
                    if (Cb) Cb[(size_t)row * ldcb + col] = __float2bfloat16(v);
                }
            }
        }
    }

    if (vquad) {   // wave-uniform; coalesced store of V^T [B',H,D,S]
        int b2 = (row0 + wr) >> 9;
        int s0 = (row0 + wr) & 511;
        int hV = gh0 - (f_qkv ? 24 : 12);
        bf16* vb = Cb2 + (((size_t)b2 * HH + hV) * DD) * SS + s0;
        #pragma unroll
        for (int p = 0; p < 8; ++p) {
            int dl = p * 8 + (l >> 3);
            int ch = l & 7;
            int cs = ch ^ (dl & 7);
            s16x8 vv = *(const s16x8*)((char*)T + dl * 128 + cs * 16);
            *(s16x8*)(vb + (size_t)dl * SS + ch * 8) = vv;
        }
    }
}

// ---------------- bf16 MFMA flash attention (batched over b') -----------------------
__global__ __launch_bounds__(256) void fattn2_kernel(
    const bf16* __restrict__ Qb, const bf16* __restrict__ Kb,
    const bf16* __restrict__ Vb, const int* __restrict__ maskE,
    bf16* __restrict__ Out, int causal)
{
    int qt = blockIdx.x, bh = blockIdx.y;
    int bp = bh / HH, h = bh % HH;     // b' (0..23 cross, 0..7 self)
    int bq = bp & 7;                   // underlying batch for Q / mask
    int tid = threadIdx.x;
    int w = tid >> 6, l = tid & 63;
    int lr = l & 15, g = l >> 4;

    __shared__ __align__(16) bf16 Qs[64 * 64];
    __shared__ __align__(16) bf16 Ks[64 * 64];
    __shared__ __align__(16) bf16 Vs[64 * 64];
    __shared__ __align__(16) bf16 Ps[64 * 64];

    int p0 = w * 1024 + l * 16;
    {
        const char* qg = (const char*)(Qb + (((size_t)bq * HH + h) * SS + qt * QT) * DD);
        #pragma unroll
        for (int i = 0; i < 2; ++i) {
            int p = i * 4096 + p0;
            int row = p >> 7, cb = p & 127;
            int scb = cb ^ ((row & 7) << 4);
            __builtin_amdgcn_global_load_lds((AS1)(qg + row * 128 + scb),
                (AS3)((char*)Qs + i * 4096 + w * 1024), 16, 0, 0);
        }
    }

    float mrun[4], lrun[4];
    f32x4 oacc[4];
    #pragma unroll
    for (int j = 0; j < 4; ++j) { mrun[j] = -3.0e38f; lrun[j] = 0.f; }
    #pragma unroll
    for (int n = 0; n < 4; ++n) oacc[n] = (f32x4){0.f, 0.f, 0.f, 0.f};

    int ntiles = causal ? (qt + 1) : (SS / KT);
    int qrow_base = w * 16;

    for (int kt = 0; kt < ntiles; ++kt) {
        const char* kg = (const char*)(Kb + ((size_t)bh * SS + kt * KT) * DD);
        const char* vg = (const char*)(Vb + (size_t)bh * DD * SS + (size_t)kt * KT);
        #pragma unroll
        for (int i = 0; i < 2; ++i) {
            int p = i * 4096 + p0;
            int row = p >> 7, cb = p & 127;
            int scb = cb ^ ((row & 7) << 4);
            __builtin_amdgcn_global_load_lds((AS1)(kg + row * 128 + scb),
                (AS3)((char*)Ks + i * 4096 + w * 1024), 16, 0, 0);
            __builtin_amdgcn_global_load_lds((AS1)(vg + (size_t)row * (SS * 2) + scb),
                (AS3)((char*)Vs + i * 4096 + w * 1024), 16, 0, 0);
        }
        int km[4];
        if (maskE) {
            #pragma unroll
            for (int n = 0; n < 4; ++n)
                km[n] = maskE[(size_t)bq * SS + kt * KT + n * 16 + lr];
        }
        __syncthreads();

        f32x4 sacc[4];
        #pragma unroll
        for (int n = 0; n < 4; ++n) sacc[n] = (f32x4){0.f, 0.f, 0.f, 0.f};
        #pragma unroll
        for (int ks = 0; ks < 2; ++ks) {
            int qrow = qrow_base + lr;
            s16x8 aq = *(const s16x8*)((const char*)Qs +
                        qrow * 128 + ((ks * 64 + g * 16) ^ ((qrow & 7) << 4)));
            #pragma unroll
            for (int n = 0; n < 4; ++n) {
                int krow = n * 16 + lr;
                s16x8 bk = *(const s16x8*)((const char*)Ks +
                            krow * 128 + ((ks * 64 + g * 16) ^ ((krow & 7) << 4)));
                sacc[n] = __builtin_amdgcn_mfma_f32_16x16x32_bf16(aq, bk, sacc[n], 0, 0, 0);
            }
        }

        #pragma unroll
        for (int n = 0; n < 4; ++n) {
            #pragma unroll
            for (int j = 0; j < 4; ++j) {
                float v = sacc[n][j] * 0.125f;
                if (causal) {
                    if (kt == qt && (n * 16 + lr > qrow_base + 4 * g + j)) v = -3.0e38f;
                } else {
                    if (km[n] != 0) v = -1e4f;
                }
                sacc[n][j] = v;
            }
        }

        float mx[4];
        #pragma unroll
        for (int j = 0; j < 4; ++j)
            mx[j] = fmaxf(fmaxf(sacc[0][j], sacc[1][j]), fmaxf(sacc[2][j], sacc[3][j]));
        #pragma unroll
        for (int msk = 1; msk < 16; msk <<= 1) {
            #pragma unroll
            for (int j = 0; j < 4; ++j) mx[j] = fmaxf(mx[j], __shfl_xor(mx[j], msk));
        }
        float rs[4], psum[4];
        #pragma unroll
        for (int j = 0; j < 4; ++j) {
            float mn = fmaxf(mrun[j], mx[j]);
            rs[j] = expf(mrun[j] - mn);
            mrun[j] = mn;
            psum[j] = 0.f;
        }
        #pragma unroll
        for (int n = 0; n < 4; ++n) {
            #pragma unroll
            for (int j = 0; j < 4; ++j) {
                float p = expf(sacc[n][j] - mrun[j]);
                psum[j] += p;
                int prow = qrow_base + 4 * g + j;
                int key = n * 16 + lr;
                *(bf16*)((char*)Ps + prow * 128 + ((2 * key) ^ ((prow & 7) << 4))) =
                    __float2bfloat16(p);
            }
        }
        #pragma unroll
        for (int msk = 1; msk < 16; msk <<= 1) {
            #pragma unroll
            for (int j = 0; j < 4; ++j) psum[j] += __shfl_xor(psum[j], msk);
        }
        #pragma unroll
        for (int j = 0; j < 4; ++j) lrun[j] = lrun[j] * rs[j] + psum[j];
        #pragma unroll
        for (int n = 0; n < 4; ++n) {
            #pragma unroll
            for (int j = 0; j < 4; ++j) oacc[n][j] *= rs[j];
        }

        #pragma unroll
        for (int ks = 0; ks < 2; ++ks) {
            int prow = qrow_base + lr;
            s16x8 ap = *(const s16x8*)((const char*)Ps +
                        prow * 128 + ((ks * 64 + g * 16) ^ ((prow & 7) << 4)));
            #pragma unroll
            for (int n = 0; n < 4; ++n) {
                int vrow = n * 16 + lr;
                s16x8 bv = *(const s16x8*)((const char*)Vs +
                            vrow * 128 + ((ks * 64 + g * 16) ^ ((vrow & 7) << 4)));
                oacc[n] = __builtin_amdgcn_mfma_f32_16x16x32_bf16(ap, bv, oacc[n], 0, 0, 0);
            }
        }
        __syncthreads();
    }

    float inv[4];
    #pragma unroll
    for (int j = 0; j < 4; ++j) inv[j] = 1.0f / lrun[j];
    #pragma unroll
    for (int n = 0; n < 4; ++n) {
        #pragma unroll
        for (int j = 0; j < 4; ++j) {
            int q = qt * QT + qrow_base + 4 * g + j;
            int d = n * 16 + lr;
            Out[((size_t)bp * SS + q) * EE + h * DD + d] =
                __float2bfloat16(oacc[n][j] * inv[j]);
        }
    }
}

// ---------------- fused 3-branch gate + /sqrt3 + maskq ------------------------------
__global__ void gate3_kernel(const float* __restrict__ logits, const float* __restrict__ a,
                             const bf16* __restrict__ e, float* __restrict__ acc,
                             const int* __restrict__ tau, const float* __restrict__ maskq)
{
    float thr = (float)tau[0];
    for (size_t i = (size_t)blockIdx.x * blockDim.x + threadIdx.x; i < NE;
         i += (size_t)gridDim.x * blockDim.x) {
        float av = a[i];
        float r = 0.f;
        #pragma unroll
        for (int idx = 0; idx < 3; ++idx) {
            float lg = logits[(size_t)idx * NE + i];
            float ev = __bfloat162float(e[(size_t)idx * NE + i]);
            float al = 1.0f / (1.0f + __expf(-lg));
            float lm = (al > thr) ? 1.0f : 0.0f;
            float vm = (al < 1.0f - thr) ? 1.0f : 0.0f;
            r += al * lm * av + (1.0f - al) * vm * ev;
        }
        acc[i] = r * 0.57735026918962576f * maskq[i / EE];
    }
}

extern "C" void kernel_launch(void* const* d_in, const int* in_sizes, int n_in,
                              void* d_out, int out_size, void* d_ws, size_t ws_size,
                              hipStream_t stream)
{
    const float* x        = (const float*)d_in[0];
    const float* enc      = (const float*)d_in[1];
    const float* maskq    = (const float*)d_in[2];
    const int*   mask_enc = (const int*)d_in[4];
    const int*   tau      = (const int*)d_in[6];
    const float* Wq = (const float*)d_in[7];
    const float* Wk = (const float*)d_in[8];
    const float* Wv = (const float*)d_in[9];
    const float* Wo = (const float*)d_in[10];
    const float* bo = (const float*)d_in[11];
    const float* fcq_w = (const float*)d_in[12];
    const float* fcq_b = (const float*)d_in[13];
    const float* fck_w = (const float*)d_in[14];
    const float* fck_b = (const float*)d_in[15];
    const float* fcv_w = (const float*)d_in[16];
    const float* fcv_b = (const float*)d_in[17];
    const float* cproj_w = (const float*)d_in[18];
    const float* cproj_b = (const float*)d_in[19];
    const float* ln1_g = (const float*)d_in[20];
    const float* ln1_b = (const float*)d_in[21];
    const float* ln2_g = (const float*)d_in[22];
    const float* ln2_b = (const float*)d_in[23];
    const float* cfc_w = (const float*)d_in[24];
    const float* cfc_b = (const float*)d_in[25];
    const float* cproj2_w = (const float*)d_in[26];
    const float* cproj2_b = (const float*)d_in[27];
    const float* aw[3] = {(const float*)d_in[28], (const float*)d_in[30], (const float*)d_in[32]};
    const float* ab[3] = {(const float*)d_in[29], (const float*)d_in[31], (const float*)d_in[33]};

    float* out   = (float*)d_out;       // [NTOK, E]
    float* kpres = out + NE;            // present K [B,H,S,D] f32 (V at +NE)

    float* ws  = (float*)d_ws;
    float* a     = ws;                  // NE f32
    float* acc   = ws + NE;             // NE f32
    float* R     = ws + 2 * NE;         // 3*NE f32, time-shared:
    bf16*  kb_c   = (bf16*)R;           //   cross K [24,H,S,D] (3 NE-bf16)
    bf16*  vb_c   = kb_c + 3 * NE;      //   cross V^T [24,H,D,S] (3 NE-bf16)
    float* logits = R;                  //   gate logits [3][NE] f32
    bf16*  mlphb  = (bf16*)R;           //   MLP hidden bf16 [NTOK][FF]

    bf16* bbase = (bf16*)(ws + 5 * NE);
    bf16* lnb   = bbase;                // u0: ln out / self-attn out (sequenced)
    bf16* atts  = bbase;                //     alias of u0
    bf16* lnenc = bbase + NE;           // u1-3: ln(enc) -> cross-attn out
    bf16* attc  = lnenc;
    bf16* a_bf  = bbase + 4 * NE;       // u4
    bf16* e_bf  = bbase + 5 * NE;       // u5-7
    bf16* qbhb  = bbase + 8 * NE;       // u8
    bf16* kbhb  = bbase + 9 * NE;       // u9 (self K)
    bf16* vbhb  = bbase + 10 * NE;      // u10 (self V^T)
    bf16* wp    = bbase + 11 * NE;      // weights
    bf16* WqkvT = wp;          wp += 3 * 768 * 768;    // [2304][768] (q|k|v)
    bf16* WoT = wp;            wp += 768 * 768;
    bf16* fcqT = wp;           wp += 768 * 768;
    bf16* fckvT = wp;          wp += 2 * 768 * 768;    // [1536][768] (k|v)
    bf16* cprojT = wp;         wp += 768 * 768;
    bf16* awT = wp;            wp += (size_t)3 * 1536 * 768;
    bf16* cfcT = wp;           wp += (size_t)768 * 3072;   // [3072][768]
    bf16* cproj2T = wp;        wp += (size_t)3072 * 768;   // [768][3072]
    float* kvb = (float*)wp;            // [1536] = fck_b|fcv_b
    float* gb  = kvb + 1536;            // [2304] = ab0|ab1|ab2

    dim3 blk(256);
    dim3 gT88(24, 24), gTaw(24, 48), gTcf(96, 24), gTcp(24, 96);

    // 0. weights -> bf16 [N][K]; concat biases (d2d async, graph-safe)
    tcast_kernel<<<gT88, blk, 0, stream>>>(Wq, WqkvT, 768, 768);
    tcast_kernel<<<gT88, blk, 0, stream>>>(Wk, WqkvT + 768 * 768, 768, 768);
    tcast_kernel<<<gT88, blk, 0, stream>>>(Wv, WqkvT + 2 * 768 * 768, 768, 768);
    tcast_kernel<<<gT88, blk, 0, stream>>>(Wo, WoT, 768, 768);
    tcast_kernel<<<gT88, blk, 0, stream>>>(fcq_w, fcqT, 768, 768);
    tcast_kernel<<<gT88, blk, 0, stream>>>(fck_w, fckvT, 768, 768);
    tcast_kernel<<<gT88, blk, 0, stream>>>(fcv_w, fckvT + 768 * 768, 768, 768);
    tcast_kernel<<<gT88, blk, 0, stream>>>(cproj_w, cprojT, 768, 768);
    tcast_kernel<<<gTaw, blk, 0, stream>>>(aw[0], awT, 1536, 768);
    tcast_kernel<<<gTaw, blk, 0, stream>>>(aw[1], awT + 1536 * 768, 1536, 768);
    tcast_kernel<<<gTaw, blk, 0, stream>>>(aw[2], awT + 2 * 1536 * 768, 1536, 768);
    tcast_kernel<<<gTcf, blk, 0, stream>>>(cfc_w, cfcT, 768, 3072);
    tcast_kernel<<<gTcp, blk, 0, stream>>>(cproj2_w, cproj2T, 3072, 768);
    hipMemcpyAsync(kvb, fck_b, 768 * 4, hipMemcpyDeviceToDevice, stream);
    hipMemcpyAsync(kvb + 768, fcv_b, 768 * 4, hipMemcpyDeviceToDevice, stream);
    hipMemcpyAsync(gb, ab[0], 768 * 4, hipMemcpyDeviceToDevice, stream);
    hipMemcpyAsync(gb + 768, ab[1], 768 * 4, hipMemcpyDeviceToDevice, stream);
    hipMemcpyAsync(gb + 1536, ab[2], 768 * 4, hipMemcpyDeviceToDevice, stream);

    // 1. xl = ln1(x)
    ln_kernel<<<NTOK, blk, 0, stream>>>(x, lnb, ln1_g, ln1_b, 0);
    // 2. fused self QKV (N=2304): q->qbhb, k->kpres+kbhb, v->vpres+vbhb(V^T)
    mgemm_kernel<<<dim3(32, 18), blk, 0, stream>>>(lnb, nullptr, WqkvT, nullptr,
        kpres, qbhb, vbhb, 0, nullptr, nullptr, 2304, 768, 768, FLAG_QKV);
    // 3. causal self-attention
    fattn2_kernel<<<dim3(8, 96), blk, 0, stream>>>(qbhb, kbhb, vbhb, nullptr, atts, 1);
    // 4. a = attout@Wo + bo + x ; bf16 copy a_bf
    mgemm_kernel<<<dim3(32, 6), blk, 0, stream>>>(atts, nullptr, WoT, bo,
        a, a_bf, nullptr, 768, x, nullptr, 768, 768, 768, FLAG_RES);
    // 5. al = ln1(a)
    ln_kernel<<<NTOK, blk, 0, stream>>>(a, lnb, ln1_g, ln1_b, 0);
    // 6. cross q
    mgemm_kernel<<<dim3(32, 6), blk, 0, stream>>>(lnb, nullptr, fcqT, fcq_b,
        nullptr, qbhb, nullptr, 0, nullptr, nullptr, 768, 768, 768, FLAG_CBSD);
    // 7. batched 3-encoder pipeline
    ln_kernel<<<3 * NTOK, blk, 0, stream>>>(enc, lnenc, ln1_g, ln1_b, 1);
    mgemm_kernel<<<dim3(96, 12), blk, 0, stream>>>(lnenc, nullptr, fckvT, kvb,
        nullptr, kb_c, vb_c, 0, nullptr, nullptr, 1536, 768, 768, FLAG_KV);
    fattn2_kernel<<<dim3(8, 288), blk, 0, stream>>>(qbhb, kb_c, vb_c, mask_enc, attc, 0);
    mgemm_kernel<<<dim3(96, 6), blk, 0, stream>>>(attc, nullptr, cprojT, cproj_b,
        nullptr, e_bf, nullptr, 768, nullptr, nullptr, 768, 768, 768, 0);
    mgemm_kernel<<<dim3(96, 6), blk, 0, stream>>>(a_bf, e_bf, awT, gb,
        logits, nullptr, nullptr, 0, nullptr, nullptr, 768, 1536, 768, FLAG_GSEG);
    gate3_kernel<<<2048, blk, 0, stream>>>(logits, a, e_bf, acc, tau, maskq);
    // 8. aqln = ln2(aq)
    ln_kernel<<<NTOK, blk, 0, stream>>>(acc, lnb, ln2_g, ln2_b, 0);
    // 9. MLP
    mgemm_kernel<<<dim3(32, 24), blk, 0, stream>>>(lnb, nullptr, cfcT, cfc_b,
        nullptr, mlphb, nullptr, 3072, nullptr, nullptr, 3072, 768, 768, FLAG_GELU);
    mgemm_kernel<<<dim3(32, 6), blk, 0, stream>>>(mlphb, nullptr, cproj2T, cproj2_b,
        out, nullptr, nullptr, 0, acc, maskq, 768, 3072, 3072, FLAG_FIN);
}

// Round 11
// 650.088 us; speedup vs baseline: 10.0513x; 1.0945x over previous
//
#include <hip/hip_runtime.h>
#include <hip/hip_bf16.h>
#include <math.h>

typedef __hip_bfloat16 bf16;
typedef __attribute__((ext_vector_type(8))) short s16x8;
typedef __attribute__((ext_vector_type(4))) float f32x4;

#define BB 8
#define SS 512
#define EE 768
#define HH 12
#define DD 64
#define FF 3072
#define NTOK (BB * SS)            // 4096
#define NE ((size_t)NTOK * EE)    // 3,145,728

#define TM 128
#define TN 128
#define TK 64

#define QT 64
#define KT 64

#define FLAG_RES  4    // + Rsrc[row,col]
#define FLAG_GELU 8
#define FLAG_FIN  16   // out = (Rsrc + v) * maskq[row]
#define FLAG_CBSD 32   // Cb store [B',H,S,D] bf16
#define FLAG_QKV  128  // self QKV fused epilogue (N=2304)
#define FLAG_KV   256  // cross K|V fused epilogue (N=1536)
#define FLAG_GSEG 512  // gate logits: per-row-seg weights, dual-source A

#define AS1 const __attribute__((address_space(1))) void*
#define AS3 __attribute__((address_space(3))) void*

__device__ __forceinline__ float gelu_new(float x) {
    // 0.5x(1+tanh(u)) == x * sigmoid(2u), u = 0.79788456(x + 0.044715 x^3)
    float u2 = 1.5957691216057308f * (x + 0.044715f * x * x * x);
    return x / (1.0f + __expf(-u2));
}

// ---------------- weight transpose+cast: src f32 [R][C] -> dst bf16 [C][R] ----------
__global__ __launch_bounds__(256) void tcast_kernel(
    const float* __restrict__ src, bf16* __restrict__ dst, int R, int C)
{
    __shared__ float t[32][33];
    int c0 = blockIdx.x * 32, r0 = blockIdx.y * 32;
    int tid = threadIdx.x;
    int x = tid & 31, y = tid >> 5;
    #pragma unroll
    for (int i = 0; i < 4; ++i) {
        int r = y + i * 8;
        t[r][x] = src[(size_t)(r0 + r) * C + c0 + x];
    }
    __syncthreads();
    #pragma unroll
    for (int i = 0; i < 4; ++i) {
        int c = y + i * 8;
        dst[(size_t)(c0 + c) * R + r0 + x] = __float2bfloat16(t[x][c]);
    }
}

// ---------------- LayerNorm (f32 in -> bf16 out); encmode decodes [B,3,S,E] ---------
__global__ __launch_bounds__(256) void ln_kernel(
    const float* __restrict__ in, bf16* __restrict__ out,
    const float* __restrict__ g, const float* __restrict__ bta, int encmode)
{
    int row = blockIdx.x;
    const float* x;
    if (encmode) {
        int idx = row >> 12, b = (row >> 9) & 7, s = row & 511;
        x = in + (((size_t)b * 3 + idx) * SS + s) * EE;
    } else {
        x = in + (size_t)row * EE;
    }
    int tid = threadIdx.x;

    float v0 = x[tid], v1 = x[tid + 256], v2 = x[tid + 512];
    float s1 = v0 + v1 + v2;
    float s2 = v0 * v0 + v1 * v1 + v2 * v2;
    #pragma unroll
    for (int o = 32; o > 0; o >>= 1) {
        s1 += __shfl_down(s1, o);
        s2 += __shfl_down(s2, o);
    }
    __shared__ float r1[4], r2[4];
    if ((tid & 63) == 0) { r1[tid >> 6] = s1; r2[tid >> 6] = s2; }
    __syncthreads();
    float mean = (r1[0] + r1[1] + r1[2] + r1[3]) * (1.0f / 768.0f);
    float ssq  = (r2[0] + r2[1] + r2[2] + r2[3]) * (1.0f / 768.0f);
    float rstd = rsqrtf(ssq - mean * mean + 1e-5f);

    bf16* y = out + (size_t)row * EE;
    y[tid]       = __float2bfloat16((v0 - mean) * rstd * g[tid]       + bta[tid]);
    y[tid + 256] = __float2bfloat16((v1 - mean) * rstd * g[tid + 256] + bta[tid + 256]);
    y[tid + 512] = __float2bfloat16((v2 - mean) * rstd * g[tid + 512] + bta[tid + 512]);
}

// ---------------- bf16 MFMA GEMM: counted-vmcnt pipeline + LDS XOR swizzle ----------
__global__ __launch_bounds__(256) void mgemm_kernel(
    const bf16* __restrict__ A, const bf16* __restrict__ A2,
    const bf16* __restrict__ Wt, const float* __restrict__ bias,
    float* __restrict__ Cf, bf16* __restrict__ Cb, bf16* __restrict__ Cb2,
    int ldcb, const float* __restrict__ Rsrc, const float* __restrict__ maskq,
    int Nn, int K, int lda, int flags)
{
    __shared__ __align__(16) bf16 smem[2 * (TM * TK + TN * TK)];   // 64 KB ring
    const int BUFE = TM * TK + TN * TK;
    int tid = threadIdx.x;
    int w = tid >> 6, l = tid & 63;

    // XCD-aware bijective swizzle (all grids have nwg % 8 == 0); row-band decode
    int gx = gridDim.x, gy = gridDim.y;
    int orig = blockIdx.y * gx + blockIdx.x;
    int cpx = (gx * gy) >> 3;
    int swz = (orig & 7) * cpx + (orig >> 3);
    int bx = swz / gy, by = swz % gy;
    int row0 = bx * TM, col0 = by * TN;

    int wr = (w >> 1) * 64, wc = (w & 1) * 64;
    int lr = l & 15, lg = l >> 4;

    bool f_res  = flags & FLAG_RES;
    bool f_gelu = flags & FLAG_GELU;
    bool f_fin  = flags & FLAG_FIN;
    bool f_cbsd = flags & FLAG_CBSD;
    bool f_qkv  = flags & FLAG_QKV;
    bool f_kv   = flags & FLAG_KV;
    bool f_gseg = flags & FLAG_GSEG;

    const bf16* Wb = Wt;
    const float* bb_ = bias;
    if (f_gseg) {
        int seg = row0 >> 12;
        Wb = Wt + (size_t)seg * 1536 * 768;
        bb_ = bias + seg * 768;
    }

    f32x4 acc[4][4];
    #pragma unroll
    for (int m = 0; m < 4; ++m)
        #pragma unroll
        for (int n = 0; n < 4; ++n) acc[m][n] = (f32x4){0.f, 0.f, 0.f, 0.f};

    // stage: linear LDS dest + inverse-swizzled global source (rule #21).
    // LDS slot (row r, elem col c) receives global elem col (c ^ ((r&7)<<3)).
    auto stage = [&](int buf, int kb) {
        bf16* As_ = smem + buf * BUFE;
        bf16* Bs_ = As_ + TM * TK;
        #pragma unroll
        for (int i = 0; i < 4; ++i) {
            int e = (i * 256 + tid) * 8;
            int r = e >> 6;
            int c = (e & 63) ^ ((r & 7) << 3);     // pre-swizzled source col
            const bf16* asrc;
            if (f_gseg) {
                int kg = kb + c;
                if (kg < 768) asrc = A  + (size_t)((row0 + r) & 4095) * lda + kg;
                else          asrc = A2 + (size_t)(row0 + r) * lda + (kg - 768);
            } else {
                asrc = A + (size_t)(row0 + r) * lda + kb + c;
            }
            __builtin_amdgcn_global_load_lds((AS1)asrc,
                (AS3)((char*)As_ + i * 4096 + w * 1024), 16, 0, 0);
            __builtin_amdgcn_global_load_lds((AS1)(Wb + (size_t)(col0 + r) * K + kb + c),
                (AS3)((char*)Bs_ + i * 4096 + w * 1024), 16, 0, 0);
        }
    };

    int nk = K / TK;
    stage(0, 0);
    for (int t = 0; t < nk; ++t) {
        int cur = t & 1;
        if (t + 1 < nk) {
            stage(cur ^ 1, (t + 1) * TK);              // 8 loads -> in flight
            asm volatile("s_waitcnt vmcnt(8)" ::: "memory");   // wait tile-t only
        } else {
            asm volatile("s_waitcnt vmcnt(0)" ::: "memory");
        }
        __builtin_amdgcn_s_barrier();                  // raw: no vmcnt drain
        __builtin_amdgcn_sched_barrier(0);

        const char* As = (const char*)(smem + cur * BUFE);
        const char* Bs = As + TM * TK * 2;
        __builtin_amdgcn_s_setprio(1);
        #pragma unroll
        for (int ks = 0; ks < 2; ++ks) {
            s16x8 af[4], bfr[4];
            #pragma unroll
            for (int m = 0; m < 4; ++m) {
                int row = wr + m * 16 + lr;
                af[m] = *(const s16x8*)(As + row * 128 +
                          ((ks * 64 + lg * 16) ^ ((row & 7) << 4)));
            }
            #pragma unroll
            for (int n = 0; n < 4; ++n) {
                int row = wc + n * 16 + lr;
                bfr[n] = *(const s16x8*)(Bs + row * 128 +
                          ((ks * 64 + lg * 16) ^ ((row & 7) << 4)));
            }
            #pragma unroll
            for (int m = 0; m < 4; ++m)
                #pragma unroll
                for (int n = 0; n < 4; ++n)
                    acc[m][n] = __builtin_amdgcn_mfma_f32_16x16x32_bf16(
                        af[m], bfr[n], acc[m][n], 0, 0, 0);
        }
        __builtin_amdgcn_s_setprio(0);
        asm volatile("s_waitcnt lgkmcnt(0)" ::: "memory");
        __builtin_amdgcn_s_barrier();                  // reads done -> buffer reusable
        __builtin_amdgcn_sched_barrier(0);
    }

    int gh0 = (col0 + wc) >> 6;
    bool vquad = (f_qkv && gh0 >= 24) || (f_kv && gh0 >= 12);
    bf16* T = smem + w * 4096;   // per-wave 8KB transpose buffer (smem dead post-loop)

    #pragma unroll
    for (int m = 0; m < 4; ++m) {
        #pragma unroll
        for (int n = 0; n < 4; ++n) {
            #pragma unroll
            for (int j = 0; j < 4; ++j) {
                int row = row0 + wr + m * 16 + lg * 4 + j;
                int col = col0 + wc + n * 16 + lr;
                size_t lin = (size_t)row * Nn + col;
                float v = acc[m][n][j];
                if (bb_)    v += bb_[col];
                if (f_res)  v += Rsrc[lin];
                if (f_gelu) v = gelu_new(v);
                if (f_fin)  v = (Rsrc[lin] + v) * maskq[row];
                int bb = row >> 9, s = row & 511;
                int gh = col >> 6, d = col & 63;
                if (f_qkv) {
                    if (gh < 12) {
                        Cb[(((size_t)bb * HH + gh) * SS + s) * DD + d] = __float2bfloat16(v);
                    } else if (gh < 24) {
                        Cf[(((size_t)bb * HH + (gh - 12)) * SS + s) * DD + d] = v;
                        Cb[NE + (((size_t)bb * HH + (gh - 12)) * SS + s) * DD + d] = __float2bfloat16(v);
                    } else {
                        Cf[NE + (((size_t)bb * HH + (gh - 24)) * SS + s) * DD + d] = v;
                        int rl = m * 16 + lg * 4 + j, cl = n * 16 + lr;
                        *(bf16*)((char*)T + cl * 128 + ((rl * 2) ^ ((cl & 7) << 4))) =
                            __float2bfloat16(v);
                    }
                } else if (f_kv) {
                    if (gh < 12) {
                        Cb[(((size_t)bb * HH + gh) * SS + s) * DD + d] = __float2bfloat16(v);
                    } else {
                        int rl = m * 16 + lg * 4 + j, cl = n * 16 + lr;
                        *(bf16*)((char*)T + cl * 128 + ((rl * 2) ^ ((cl & 7) << 4))) =
                            __float2bfloat16(v);
                    }
                } else if (f_cbsd) {
                    Cb[(((size_t)bb * HH + gh) * SS + s) * DD + d] = __float2bfloat16(v);
                } else {
                    if (Cf) Cf[lin] = v;
                    if (Cb) Cb[(size_t)row * ldcb + col] = __float2bfloat16(v);
                }
            }
        }
    }

    if (vquad) {   // wave-uniform; coalesced store of V^T [B',H,D,S]
        int b2 = (row0 + wr) >> 9;
        int s0 = (row0 + wr) & 511;
        int hV = gh0 - (f_qkv ? 24 : 12);
        bf16* vb = Cb2 + (((size_t)b2 * HH + hV) * DD) * SS + s0;
        #pragma unroll
        for (int p = 0; p < 8; ++p) {
            int dl = p * 8 + (l >> 3);
            int ch = l & 7;
            int cs = ch ^ (dl & 7);
            s16x8 vv = *(const s16x8*)((char*)T + dl * 128 + cs * 16);
            *(s16x8*)(vb + (size_t)dl * SS + ch * 8) = vv;
        }
    }
}

// ---------------- bf16 MFMA flash attention (batched over b') -----------------------
__global__ __launch_bounds__(256) void fattn2_kernel(
    const bf16* __restrict__ Qb, const bf16* __restrict__ Kb,
    const bf16* __restrict__ Vb, const int* __restrict__ maskE,
    bf16* __restrict__ Out, int causal)
{
    int qt = blockIdx.x, bh = blockIdx.y;
    int bp = bh / HH, h = bh % HH;     // b' (0..23 cross, 0..7 self)
    int bq = bp & 7;                   // underlying batch for Q / mask
    int tid = threadIdx.x;
    int w = tid >> 6, l = tid & 63;
    int lr = l & 15, g = l >> 4;

    __shared__ __align__(16) bf16 Qs[64 * 64];
    __shared__ __align__(16) bf16 Ks[64 * 64];
    __shared__ __align__(16) bf16 Vs[64 * 64];
    __shared__ __align__(16) bf16 Ps[64 * 64];

    int p0 = w * 1024 + l * 16;
    {
        const char* qg = (const char*)(Qb + (((size_t)bq * HH + h) * SS + qt * QT) * DD);
        #pragma unroll
        for (int i = 0; i < 2; ++i) {
            int p = i * 4096 + p0;
            int row = p >> 7, cb = p & 127;
            int scb = cb ^ ((row & 7) << 4);
            __builtin_amdgcn_global_load_lds((AS1)(qg + row * 128 + scb),
                (AS3)((char*)Qs + i * 4096 + w * 1024), 16, 0, 0);
        }
    }

    float mrun[4], lrun[4];
    f32x4 oacc[4];
    #pragma unroll
    for (int j = 0; j < 4; ++j) { mrun[j] = -3.0e38f; lrun[j] = 0.f; }
    #pragma unroll
    for (int n = 0; n < 4; ++n) oacc[n] = (f32x4){0.f, 0.f, 0.f, 0.f};

    int ntiles = causal ? (qt + 1) : (SS / KT);
    int qrow_base = w * 16;

    for (int kt = 0; kt < ntiles; ++kt) {
        const char* kg = (const char*)(Kb + ((size_t)bh * SS + kt * KT) * DD);
        const char* vg = (const char*)(Vb + (size_t)bh * DD * SS + (size_t)kt * KT);
        #pragma unroll
        for (int i = 0; i < 2; ++i) {
            int p = i * 4096 + p0;
            int row = p >> 7, cb = p & 127;
            int scb = cb ^ ((row & 7) << 4);
            __builtin_amdgcn_global_load_lds((AS1)(kg + row * 128 + scb),
                (AS3)((char*)Ks + i * 4096 + w * 1024), 16, 0, 0);
            __builtin_amdgcn_global_load_lds((AS1)(vg + (size_t)row * (SS * 2) + scb),
                (AS3)((char*)Vs + i * 4096 + w * 1024), 16, 0, 0);
        }
        int km[4];
        if (maskE) {
            #pragma unroll
            for (int n = 0; n < 4; ++n)
                km[n] = maskE[(size_t)bq * SS + kt * KT + n * 16 + lr];
        }
        __syncthreads();

        f32x4 sacc[4];
        #pragma unroll
        for (int n = 0; n < 4; ++n) sacc[n] = (f32x4){0.f, 0.f, 0.f, 0.f};
        #pragma unroll
        for (int ks = 0; ks < 2; ++ks) {
            int qrow = qrow_base + lr;
            s16x8 aq = *(const s16x8*)((const char*)Qs +
                        qrow * 128 + ((ks * 64 + g * 16) ^ ((qrow & 7) << 4)));
            #pragma unroll
            for (int n = 0; n < 4; ++n) {
                int krow = n * 16 + lr;
                s16x8 bk = *(const s16x8*)((const char*)Ks +
                            krow * 128 + ((ks * 64 + g * 16) ^ ((krow & 7) << 4)));
                sacc[n] = __builtin_amdgcn_mfma_f32_16x16x32_bf16(aq, bk, sacc[n], 0, 0, 0);
            }
        }

        #pragma unroll
        for (int n = 0; n < 4; ++n) {
            #pragma unroll
            for (int j = 0; j < 4; ++j) {
                float v = sacc[n][j] * 0.125f;
                if (causal) {
                    if (kt == qt && (n * 16 + lr > qrow_base + 4 * g + j)) v = -3.0e38f;
                } else {
                    if (km[n] != 0) v = -1e4f;
                }
                sacc[n][j] = v;
            }
        }

        float mx[4];
        #pragma unroll
        for (int j = 0; j < 4; ++j)
            mx[j] = fmaxf(fmaxf(sacc[0][j], sacc[1][j]), fmaxf(sacc[2][j], sacc[3][j]));
        #pragma unroll
        for (int msk = 1; msk < 16; msk <<= 1) {
            #pragma unroll
            for (int j = 0; j < 4; ++j) mx[j] = fmaxf(mx[j], __shfl_xor(mx[j], msk));
        }
        float rs[4], psum[4];
        #pragma unroll
        for (int j = 0; j < 4; ++j) {
            float mn = fmaxf(mrun[j], mx[j]);
            rs[j] = expf(mrun[j] - mn);
            mrun[j] = mn;
            psum[j] = 0.f;
        }
        #pragma unroll
        for (int n = 0; n < 4; ++n) {
            #pragma unroll
            for (int j = 0; j < 4; ++j) {
                float p = expf(sacc[n][j] - mrun[j]);
                psum[j] += p;
                int prow = qrow_base + 4 * g + j;
                int key = n * 16 + lr;
                *(bf16*)((char*)Ps + prow * 128 + ((2 * key) ^ ((prow & 7) << 4))) =
                    __float2bfloat16(p);
            }
        }
        #pragma unroll
        for (int msk = 1; msk < 16; msk <<= 1) {
            #pragma unroll
            for (int j = 0; j < 4; ++j) psum[j] += __shfl_xor(psum[j], msk);
        }
        #pragma unroll
        for (int j = 0; j < 4; ++j) lrun[j] = lrun[j] * rs[j] + psum[j];
        #pragma unroll
        for (int n = 0; n < 4; ++n) {
            #pragma unroll
            for (int j = 0; j < 4; ++j) oacc[n][j] *= rs[j];
        }

        #pragma unroll
        for (int ks = 0; ks < 2; ++ks) {
            int prow = qrow_base + lr;
            s16x8 ap = *(const s16x8*)((const char*)Ps +
                        prow * 128 + ((ks * 64 + g * 16) ^ ((prow & 7) << 4)));
            #pragma unroll
            for (int n = 0; n < 4; ++n) {
                int vrow = n * 16 + lr;
                s16x8 bv = *(const s16x8*)((const char*)Vs +
                            vrow * 128 + ((ks * 64 + g * 16) ^ ((vrow & 7) << 4)));
                oacc[n] = __builtin_amdgcn_mfma_f32_16x16x32_bf16(ap, bv, oacc[n], 0, 0, 0);
            }
        }
        __syncthreads();
    }

    float inv[4];
    #pragma unroll
    for (int j = 0; j < 4; ++j) inv[j] = 1.0f / lrun[j];
    #pragma unroll
    for (int n = 0; n < 4; ++n) {
        #pragma unroll
        for (int j = 0; j < 4; ++j) {
            int q = qt * QT + qrow_base + 4 * g + j;
            int d = n * 16 + lr;
            Out[((size_t)bp * SS + q) * EE + h * DD + d] =
                __float2bfloat16(oacc[n][j] * inv[j]);
        }
    }
}

// ---------------- fused 3-branch gate + /sqrt3 + maskq ------------------------------
__global__ void gate3_kernel(const float* __restrict__ logits, const float* __restrict__ a,
                             const bf16* __restrict__ e, float* __restrict__ acc,
                             const int* __restrict__ tau, const float* __restrict__ maskq)
{
    float thr = (float)tau[0];
    for (size_t i = (size_t)blockIdx.x * blockDim.x + threadIdx.x; i < NE;
         i += (size_t)gridDim.x * blockDim.x) {
        float av = a[i];
        float r = 0.f;
        #pragma unroll
        for (int idx = 0; idx < 3; ++idx) {
            float lg = logits[(size_t)idx * NE + i];
            float ev = __bfloat162float(e[(size_t)idx * NE + i]);
            float al = 1.0f / (1.0f + __expf(-lg));
            float lm = (al > thr) ? 1.0f : 0.0f;
            float vm = (al < 1.0f - thr) ? 1.0f : 0.0f;
            r += al * lm * av + (1.0f - al) * vm * ev;
        }
        acc[i] = r * 0.57735026918962576f * maskq[i / EE];
    }
}

extern "C" void kernel_launch(void* const* d_in, const int* in_sizes, int n_in,
                              void* d_out, int out_size, void* d_ws, size_t ws_size,
                              hipStream_t stream)
{
    const float* x        = (const float*)d_in[0];
    const float* enc      = (const float*)d_in[1];
    const float* maskq    = (const float*)d_in[2];
    const int*   mask_enc = (const int*)d_in[4];
    const int*   tau      = (const int*)d_in[6];
    const float* Wq = (const float*)d_in[7];
    const float* Wk = (const float*)d_in[8];
    const float* Wv = (const float*)d_in[9];
    const float* Wo = (const float*)d_in[10];
    const float* bo = (const float*)d_in[11];
    const float* fcq_w = (const float*)d_in[12];
    const float* fcq_b = (const float*)d_in[13];
    const float* fck_w = (const float*)d_in[14];
    const float* fck_b = (const float*)d_in[15];
    const float* fcv_w = (const float*)d_in[16];
    const float* fcv_b = (const float*)d_in[17];
    const float* cproj_w = (const float*)d_in[18];
    const float* cproj_b = (const float*)d_in[19];
    const float* ln1_g = (const float*)d_in[20];
    const float* ln1_b = (const float*)d_in[21];
    const float* ln2_g = (const float*)d_in[22];
    const float* ln2_b = (const float*)d_in[23];
    const float* cfc_w = (const float*)d_in[24];
    const float* cfc_b = (const float*)d_in[25];
    const float* cproj2_w = (const float*)d_in[26];
    const float* cproj2_b = (const float*)d_in[27];
    const float* aw[3] = {(const float*)d_in[28], (const float*)d_in[30], (const float*)d_in[32]};
    const float* ab[3] = {(const float*)d_in[29], (const float*)d_in[31], (const float*)d_in[33]};

    float* out   = (float*)d_out;       // [NTOK, E]
    float* kpres = out + NE;            // present K [B,H,S,D] f32 (V at +NE)

    float* ws  = (float*)d_ws;
    float* a     = ws;                  // NE f32
    float* acc   = ws + NE;             // NE f32
    float* R     = ws + 2 * NE;         // 3*NE f32, time-shared:
    bf16*  kb_c   = (bf16*)R;           //   cross K [24,H,S,D] (3 NE-bf16)
    bf16*  vb_c   = kb_c + 3 * NE;      //   cross V^T [24,H,D,S] (3 NE-bf16)
    float* logits = R;                  //   gate logits [3][NE] f32
    bf16*  mlphb  = (bf16*)R;           //   MLP hidden bf16 [NTOK][FF]

    bf16* bbase = (bf16*)(ws + 5 * NE);
    bf16* lnb   = bbase;                // u0: ln out / self-attn out (sequenced)
    bf16* atts  = bbase;                //     alias of u0
    bf16* lnenc = bbase + NE;           // u1-3: ln(enc) -> cross-attn out
    bf16* attc  = lnenc;
    bf16* a_bf  = bbase + 4 * NE;       // u4
    bf16* e_bf  = bbase + 5 * NE;       // u5-7
    bf16* qbhb  = bbase + 8 * NE;       // u8
    bf16* kbhb  = bbase + 9 * NE;       // u9 (self K)
    bf16* vbhb  = bbase + 10 * NE;      // u10 (self V^T)
    bf16* wp    = bbase + 11 * NE;      // weights
    bf16* WqkvT = wp;          wp += 3 * 768 * 768;    // [2304][768] (q|k|v)
    bf16* WoT = wp;            wp += 768 * 768;
    bf16* fcqT = wp;           wp += 768 * 768;
    bf16* fckvT = wp;          wp += 2 * 768 * 768;    // [1536][768] (k|v)
    bf16* cprojT = wp;         wp += 768 * 768;
    bf16* awT = wp;            wp += (size_t)3 * 1536 * 768;
    bf16* cfcT = wp;           wp += (size_t)768 * 3072;   // [3072][768]
    bf16* cproj2T = wp;        wp += (size_t)3072 * 768;   // [768][3072]
    float* kvb = (float*)wp;            // [1536] = fck_b|fcv_b
    float* gb  = kvb + 1536;            // [2304] = ab0|ab1|ab2

    dim3 blk(256);
    dim3 gT88(24, 24), gTaw(24, 48), gTcf(96, 24), gTcp(24, 96);

    // 0. weights -> bf16 [N][K]; concat biases (d2d async, graph-safe)
    tcast_kernel<<<gT88, blk, 0, stream>>>(Wq, WqkvT, 768, 768);
    tcast_kernel<<<gT88, blk, 0, stream>>>(Wk, WqkvT + 768 * 768, 768, 768);
    tcast_kernel<<<gT88, blk, 0, stream>>>(Wv, WqkvT + 2 * 768 * 768, 768, 768);
    tcast_kernel<<<gT88, blk, 0, stream>>>(Wo, WoT, 768, 768);
    tcast_kernel<<<gT88, blk, 0, stream>>>(fcq_w, fcqT, 768, 768);
    tcast_kernel<<<gT88, blk, 0, stream>>>(fck_w, fckvT, 768, 768);
    tcast_kernel<<<gT88, blk, 0, stream>>>(fcv_w, fckvT + 768 * 768, 768, 768);
    tcast_kernel<<<gT88, blk, 0, stream>>>(cproj_w, cprojT, 768, 768);
    tcast_kernel<<<gTaw, blk, 0, stream>>>(aw[0], awT, 1536, 768);
    tcast_kernel<<<gTaw, blk, 0, stream>>>(aw[1], awT + 1536 * 768, 1536, 768);
    tcast_kernel<<<gTaw, blk, 0, stream>>>(aw[2], awT + 2 * 1536 * 768, 1536, 768);
    tcast_kernel<<<gTcf, blk, 0, stream>>>(cfc_w, cfcT, 768, 3072);
    tcast_kernel<<<gTcp, blk, 0, stream>>>(cproj2_w, cproj2T, 3072, 768);
    hipMemcpyAsync(kvb, fck_b, 768 * 4, hipMemcpyDeviceToDevice, stream);
    hipMemcpyAsync(kvb + 768, fcv_b, 768 * 4, hipMemcpyDeviceToDevice, stream);
    hipMemcpyAsync(gb, ab[0], 768 * 4, hipMemcpyDeviceToDevice, stream);
    hipMemcpyAsync(gb + 768, ab[1], 768 * 4, hipMemcpyDeviceToDevice, stream);
    hipMemcpyAsync(gb + 1536, ab[2], 768 * 4, hipMemcpyDeviceToDevice, stream);

    // 1. xl = ln1(x)
    ln_kernel<<<NTOK, blk, 0, stream>>>(x, lnb, ln1_g, ln1_b, 0);
    // 2. fused self QKV (N=2304): q->qbhb, k->kpres+kbhb, v->vpres+vbhb(V^T)
    mgemm_kernel<<<dim3(32, 18), blk, 0, stream>>>(lnb, nullptr, WqkvT, nullptr,
        kpres, qbhb, vbhb, 0, nullptr, nullptr, 2304, 768, 768, FLAG_QKV);
    // 3. causal self-attention
    fattn2_kernel<<<dim3(8, 96), blk, 0, stream>>>(qbhb, kbhb, vbhb, nullptr, atts, 1);
    // 4. a = attout@Wo + bo + x ; bf16 copy a_bf
    mgemm_kernel<<<dim3(32, 6), blk, 0, stream>>>(atts, nullptr, WoT, bo,
        a, a_bf, nullptr, 768, x, nullptr, 768, 768, 768, FLAG_RES);
    // 5. al = ln1(a)
    ln_kernel<<<NTOK, blk, 0, stream>>>(a, lnb, ln1_g, ln1_b, 0);
    // 6. cross q
    mgemm_kernel<<<dim3(32, 6), blk, 0, stream>>>(lnb, nullptr, fcqT, fcq_b,
        nullptr, qbhb, nullptr, 0, nullptr, nullptr, 768, 768, 768, FLAG_CBSD);
    // 7. batched 3-encoder pipeline
    ln_kernel<<<3 * NTOK, blk, 0, stream>>>(enc, lnenc, ln1_g, ln1_b, 1);
    mgemm_kernel<<<dim3(96, 12), blk, 0, stream>>>(lnenc, nullptr, fckvT, kvb,
        nullptr, kb_c, vb_c, 0, nullptr, nullptr, 1536, 768, 768, FLAG_KV);
    fattn2_kernel<<<dim3(8, 288), blk, 0, stream>>>(qbhb, kb_c, vb_c, mask_enc, attc, 0);
    mgemm_kernel<<<dim3(96, 6), blk, 0, stream>>>(attc, nullptr, cprojT, cproj_b,
        nullptr, e_bf, nullptr, 768, nullptr, nullptr, 768, 768, 768, 0);
    mgemm_kernel<<<dim3(96, 6), blk, 0, stream>>>(a_bf, e_bf, awT, gb,
        logits, nullptr, nullptr, 0, nullptr, nullptr, 768, 1536, 768, FLAG_GSEG);
    gate3_kernel<<<2048, blk, 0, stream>>>(logits, a, e_bf, acc, tau, maskq);
    // 8. aqln = ln2(aq)
    ln_kernel<<<NTOK, blk, 0, stream>>>(acc, lnb, ln2_g, ln2_b, 0);
    // 9. MLP
    mgemm_kernel<<<dim3(32, 24), blk, 0, stream>>>(lnb, nullptr, cfcT, cfc_b,
        nullptr, mlphb, nullptr, 3072, nullptr, nullptr, 3072, 768, 768, FLAG_GELU);
    mgemm_kernel<<<dim3(32, 6), blk, 0, stream>>>(mlphb, nullptr, cproj2T, cproj2_b,
        out, nullptr, nullptr, 0, acc, maskq, 768, 3072, 3072, FLAG_FIN);
}